// Round 10
// baseline (642.842 us; speedup 1.0000x reference)
//
#include <hip/hip_runtime.h>
#include <hip/hip_bf16.h>

#define H 128
#define DOUT 32
#define NGRAPH 64
#define PCHUNK 128
#define SORT_TILE 2048
#define NBUCK_MAX 128
#define AGG_ROWS 32  // rows per agg block (4 waves x 8 subwaves)

typedef __attribute__((ext_vector_type(8))) short bf16x8;
typedef __attribute__((ext_vector_type(4))) float f32x4;
union U4B {
    uint4 u;
    bf16x8 b;
};

// bf16 helpers (RTN-even pack, bit-shift unpack)
static __device__ __forceinline__ unsigned short f2bf(float v) {
    unsigned int u = __float_as_uint(v);
    unsigned int r = (u + 0x7FFFu + ((u >> 16) & 1u)) >> 16;
    return (unsigned short)r;
}
#define BFLO(w) __uint_as_float((w) << 16)
#define BFHI(w) __uint_as_float((w) & 0xFFFF0000u)

// ---------------- edge bucket sort (by dst >> bshift) ----------------

__global__ __launch_bounds__(256) void bucket_hist_kernel(const int* __restrict__ dst, int E,
                                                          int bshift, int* __restrict__ bcnt) {
    __shared__ int lh[NBUCK_MAX];
    int t = threadIdx.x;
    if (t < NBUCK_MAX) lh[t] = 0;
    __syncthreads();
    int base = blockIdx.x * SORT_TILE;
    int cnt = E - base;
    if (cnt > SORT_TILE) cnt = SORT_TILE;
    for (int j = t; j < cnt; j += 256) atomicAdd(&lh[dst[base + j] >> bshift], 1);
    __syncthreads();
    if (t < NBUCK_MAX && lh[t]) atomicAdd(&bcnt[t], lh[t]);
}

__global__ void bucket_scan_kernel(const int* __restrict__ bcnt, int* __restrict__ bfill,
                                   int nbuck) {
    if (threadIdx.x == 0) {
        int run = 0;
        for (int b = 0; b < nbuck; ++b) {
            bfill[b] = run;
            run += bcnt[b];
        }
    }
}

__global__ __launch_bounds__(256) void bucket_scatter_kernel(const int* __restrict__ src,
                                                             const int* __restrict__ dst, int E,
                                                             int bshift, int* __restrict__ bfill,
                                                             int2* __restrict__ es) {
    __shared__ int lh[NBUCK_MAX], lsc[NBUCK_MAX], lbase[NBUCK_MAX], lfill[NBUCK_MAX],
        ldelta[NBUCK_MAX];
    __shared__ int2 sp[SORT_TILE];
    __shared__ unsigned char sb[SORT_TILE];
    int t = threadIdx.x;
    if (t < NBUCK_MAX) {
        lh[t] = 0;
        lfill[t] = 0;
    }
    __syncthreads();
    int base = blockIdx.x * SORT_TILE;
    int cnt = E - base;
    if (cnt > SORT_TILE) cnt = SORT_TILE;
    for (int j = t; j < cnt; j += 256) atomicAdd(&lh[dst[base + j] >> bshift], 1);
    __syncthreads();
    if (t < NBUCK_MAX) lsc[t] = lh[t];
    __syncthreads();
    for (int off = 1; off < NBUCK_MAX; off <<= 1) {
        int x = 0;
        if (t < NBUCK_MAX && t >= off) x = lsc[t - off];
        __syncthreads();
        if (t < NBUCK_MAX) lsc[t] += x;
        __syncthreads();
    }
    if (t < NBUCK_MAX) {
        lbase[t] = lsc[t] - lh[t];
        if (lh[t] > 0) ldelta[t] = atomicAdd(&bfill[t], lh[t]) - lbase[t];
    }
    __syncthreads();
    for (int j = t; j < cnt; j += 256) {
        int s = src[base + j], d = dst[base + j];
        int b = d >> bshift;
        int r = atomicAdd(&lfill[b], 1);
        int slot = lbase[b] + r;
        sp[slot] = make_int2(s, d);
        sb[slot] = (unsigned char)b;
    }
    __syncthreads();
    for (int j = t; j < cnt; j += 256) {
        int b = sb[j];
        es[ldelta[b] + j] = sp[j];
    }
}

// deg histogram over bucket-sorted edges: block window = 1-2 buckets (4-8KB)
__global__ __launch_bounds__(256) void deg_hist_sorted(const int2* __restrict__ es, int E,
                                                       int* __restrict__ deg) {
    int e = blockIdx.x * 256 + threadIdx.x;
    if (e < E) atomicAdd(&deg[es[e].y], 1);
}

__global__ __launch_bounds__(256) void fill_csr_sorted(const int2* __restrict__ es, int E,
                                                       int* __restrict__ fill,
                                                       int* __restrict__ col) {
    int e = blockIdx.x * 256 + threadIdx.x;
    if (e < E) {
        int2 p = es[e];
        int pos = atomicAdd(&fill[p.y], 1);
        col[pos] = p.x;
    }
}

// ---------------- CSR row_ptr scan / misc ----------------

__global__ __launch_bounds__(256) void batch_bounds_kernel(const int* __restrict__ batch,
                                                           int N, int* __restrict__ gstart) {
    int i = blockIdx.x * 256 + threadIdx.x;
    if (i < N) {
        int b = batch[i];
        int bp = (i == 0) ? -1 : batch[i - 1];
        for (int g = bp + 1; g <= b; ++g) gstart[g] = i;
        if (i == N - 1)
            for (int g = b + 1; g <= NGRAPH; ++g) gstart[g] = N;
    }
}

__global__ __launch_bounds__(256) void scan_phase1(const int* __restrict__ deg, int N,
                                                   int* __restrict__ bsum) {
    __shared__ int sd[256];
    int t = threadIdx.x;
    int base = blockIdx.x * 1024 + t * 4;
    int s = 0;
#pragma unroll
    for (int j = 0; j < 4; ++j)
        if (base + j < N) s += deg[base + j];
    sd[t] = s;
    __syncthreads();
    for (int off = 128; off > 0; off >>= 1) {
        if (t < off) sd[t] += sd[t + off];
        __syncthreads();
    }
    if (t == 0) bsum[blockIdx.x] = sd[0];
}

__global__ void scan_phase2(int* bsum, int nb, int* __restrict__ row_ptr, int N, int E) {
    if (threadIdx.x == 0) {
        int run = 0;
        for (int i = 0; i < nb; ++i) {
            int v = bsum[i];
            bsum[i] = run;
            run += v;
        }
        row_ptr[N] = E;
    }
}

// scan_phase3 + init_node fused: emits row_ptr, fill copy, dinv
__global__ __launch_bounds__(256) void scan_phase3(const int* __restrict__ deg,
                                                   const int* __restrict__ boff, int N,
                                                   int* __restrict__ row_ptr,
                                                   int* __restrict__ fill,
                                                   float* __restrict__ dinv) {
    __shared__ int sd[256];
    int t = threadIdx.x;
    int base = blockIdx.x * 1024 + t * 4;
    int v[4];
    int s = 0;
#pragma unroll
    for (int j = 0; j < 4; ++j) {
        v[j] = (base + j < N) ? deg[base + j] : 0;
        s += v[j];
    }
    sd[t] = s;
    __syncthreads();
    for (int off = 1; off < 256; off <<= 1) {
        int x = (t >= off) ? sd[t - off] : 0;
        __syncthreads();
        sd[t] += x;
        __syncthreads();
    }
    int run = boff[blockIdx.x] + sd[t] - s;
#pragma unroll
    for (int j = 0; j < 4; ++j)
        if (base + j < N) {
            row_ptr[base + j] = run;
            fill[base + j] = run;
            dinv[base + j] = rsqrtf(1.0f + (float)v[j]);
            run += v[j];
        }
}

// ---------------- W preprocessing (both weights in one dispatch) ----------------

__global__ __launch_bounds__(256) void prep_w_kernel(const float* __restrict__ W1,
                                                     const float* __restrict__ W2,
                                                     unsigned int* __restrict__ Wbf1,
                                                     unsigned int* __restrict__ Wbf2) {
    int b = blockIdx.x;
    const float* W = (b < 32) ? W1 : W2;
    unsigned int* Wbf = (b < 32) ? Wbf1 : Wbf2;
    int q = (b & 31) * 256 + threadIdx.x;  // 0..8191
    int colq = q >> 6, j = q & 63;
    int p = j >> 2, wI = j & 3;
    int cq = p ^ (colq & 15);
    int k0 = 8 * cq + 2 * wI;
    Wbf[q] = (unsigned int)f2bf(W[k0 * H + colq]) |
             ((unsigned int)f2bf(W[(k0 + 1) * H + colq]) << 16);
}

// ---------------- MFMA matmul ----------------
template <int IN_BF16>
__global__ __launch_bounds__(256) void mm_mfma_kernel(const void* __restrict__ Xv,
                                                      const unsigned int* __restrict__ Wbf,
                                                      const float* __restrict__ dinv,
                                                      unsigned short* __restrict__ Out, int M) {
    __shared__ unsigned int wlds[128 * 64];
    int t = threadIdx.x;
    const uint4* Wv = (const uint4*)Wbf;
#pragma unroll
    for (int it = 0; it < 8; ++it)
        ((uint4*)wlds)[t + it * 256] = Wv[t + it * 256];
    __syncthreads();

    int wv = t >> 6, l = t & 63;
    int l16 = l & 15, lk = l >> 4;
    int rowbase = blockIdx.x * 128 + wv * 32;

    f32x4 acc[2][8];
#pragma unroll
    for (int rt = 0; rt < 2; ++rt)
#pragma unroll
        for (int nt = 0; nt < 8; ++nt) acc[rt][nt] = (f32x4){0.f, 0.f, 0.f, 0.f};

#pragma unroll
    for (int ks = 0; ks < 4; ++ks) {
        U4B afr[2];
#pragma unroll
        for (int rt = 0; rt < 2; ++rt) {
            int row = rowbase + rt * 16 + l16;
            if (IN_BF16) {
                uint4 v = make_uint4(0u, 0u, 0u, 0u);
                if (row < M) v = *((const uint4*)Xv + (size_t)row * 16 + 4 * ks + lk);
                afr[rt].u = v;
            } else {
                const float* X = (const float*)Xv;
                float4 v0 = make_float4(0.f, 0.f, 0.f, 0.f), v1 = v0;
                if (row < M) {
                    v0 = *reinterpret_cast<const float4*>(X + (size_t)row * H + 32 * ks +
                                                          8 * lk);
                    v1 = *reinterpret_cast<const float4*>(X + (size_t)row * H + 32 * ks +
                                                          8 * lk + 4);
                }
                afr[rt].u.x = (unsigned int)f2bf(v0.x) | ((unsigned int)f2bf(v0.y) << 16);
                afr[rt].u.y = (unsigned int)f2bf(v0.z) | ((unsigned int)f2bf(v0.w) << 16);
                afr[rt].u.z = (unsigned int)f2bf(v1.x) | ((unsigned int)f2bf(v1.y) << 16);
                afr[rt].u.w = (unsigned int)f2bf(v1.z) | ((unsigned int)f2bf(v1.w) << 16);
            }
        }
#pragma unroll
        for (int nt = 0; nt < 8; ++nt) {
            int colB = nt * 16 + l16;
            int c = 4 * ks + lk;
            int p = c ^ (colB & 15);
            U4B bfr;
            bfr.u = *reinterpret_cast<const uint4*>(&wlds[colB * 64 + p * 4]);
            acc[0][nt] = __builtin_amdgcn_mfma_f32_16x16x32_bf16(afr[0].b, bfr.b, acc[0][nt],
                                                                 0, 0, 0);
            acc[1][nt] = __builtin_amdgcn_mfma_f32_16x16x32_bf16(afr[1].b, bfr.b, acc[1][nt],
                                                                 0, 0, 0);
        }
    }

#pragma unroll
    for (int rt = 0; rt < 2; ++rt) {
#pragma unroll
        for (int r = 0; r < 4; ++r) {
            int row = rowbase + rt * 16 + lk * 4 + r;
            if (row < M) {
                float dsc = dinv[row];
#pragma unroll
                for (int nt = 0; nt < 8; ++nt)
                    Out[(size_t)row * H + nt * 16 + l16] = f2bf(acc[rt][nt][r] * dsc);
            }
        }
    }
}

// ---------------- aggregation: XCD-pinned feature slices ----------------
// slice = blockIdx.x & 7 (round-robin block->XCD => each XCD's L2 holds only
// its 16-feature slice of Au: 100K rows x 32B = 3.2MB < 4MB L2).
// Block = 4 waves x 8 subwaves; subwave (8 lanes) owns one dst row; lane owns
// one u32 (2 bf16 features) of the slice.
__global__ __launch_bounds__(256) void agg_bf16_sliced(
    const unsigned int* __restrict__ Au, const int* __restrict__ row_ptr,
    const int* __restrict__ col, const float* __restrict__ dinv,
    const float* __restrict__ bias, unsigned int* __restrict__ OutBf, int N) {
    int bid = blockIdx.x;
    int slice = bid & 7;
    int rbase = (bid >> 3) * AGG_ROWS;
    int t = threadIdx.x;
    int wave = t >> 6, l = t & 63;
    int subrow = l >> 3, fu = l & 7;
    int i = rbase + wave * 8 + subrow;
    if (i >= N) return;
    int fidx = slice * 8 + fu;  // u32 index within row [0,64)
    int s = row_ptr[i], e = row_ptr[i + 1];
    unsigned int ws = Au[(size_t)i * 64 + fidx];  // self-loop term
    float acc0 = BFLO(ws), acc1 = BFHI(ws);
    int j = s;
    for (; j + 4 <= e; j += 4) {
        int c0 = col[j], c1 = col[j + 1], c2 = col[j + 2], c3 = col[j + 3];
        unsigned int w0 = Au[(size_t)c0 * 64 + fidx];
        unsigned int w1 = Au[(size_t)c1 * 64 + fidx];
        unsigned int w2 = Au[(size_t)c2 * 64 + fidx];
        unsigned int w3 = Au[(size_t)c3 * 64 + fidx];
        acc0 += BFLO(w0) + BFLO(w1);
        acc1 += BFHI(w0) + BFHI(w1);
        acc0 += BFLO(w2) + BFLO(w3);
        acc1 += BFHI(w2) + BFHI(w3);
    }
    for (; j < e; ++j) {
        unsigned int w = Au[(size_t)col[j] * 64 + fidx];
        acc0 += BFLO(w);
        acc1 += BFHI(w);
    }
    float d = dinv[i];
    float o0 = fmaxf(fmaf(d, acc0, bias[2 * fidx]), 0.f);
    float o1 = fmaxf(fmaf(d, acc1, bias[2 * fidx + 1]), 0.f);
    OutBf[(size_t)i * 64 + fidx] = (unsigned int)f2bf(o0) | ((unsigned int)f2bf(o1) << 16);
}

// ---------------- pooling (bf16 input, register pre-reduction) ----------------

__global__ __launch_bounds__(64) void pool_partial(const unsigned int* __restrict__ Bu,
                                                   const int* __restrict__ batch,
                                                   float* __restrict__ gsum, int N) {
    __shared__ int sb[PCHUNK];
    int base = blockIdx.x * PCHUNK;
    int n_here = N - base;
    if (n_here > PCHUNK) n_here = PCHUNK;
    int f = threadIdx.x;  // u32 feature-pair index 0..63
    for (int j = f; j < n_here; j += 64) sb[j] = batch[base + j];
    __syncthreads();
    float acc0 = 0.f, acc1 = 0.f;
    int cur = sb[0];
    for (int j = 0; j < n_here; ++j) {
        int g = sb[j];  // wave-uniform
        if (g != cur) {
            atomicAdd(&gsum[cur * H + 2 * f], acc0);
            atomicAdd(&gsum[cur * H + 2 * f + 1], acc1);
            acc0 = 0.f;
            acc1 = 0.f;
            cur = g;
        }
        unsigned int w = Bu[(size_t)(base + j) * 64 + f];
        acc0 += BFLO(w);
        acc1 += BFHI(w);
    }
    atomicAdd(&gsum[cur * H + 2 * f], acc0);
    atomicAdd(&gsum[cur * H + 2 * f + 1], acc1);
}

// head + pool_final fused: gv = gsum/cnt
__global__ __launch_bounds__(128) void head_kernel(const float* __restrict__ gsum,
                                                   const int* __restrict__ gstart,
                                                   const float* __restrict__ fW1,
                                                   const float* __restrict__ fb1,
                                                   const float* __restrict__ fW2,
                                                   const float* __restrict__ fb2,
                                                   float* __restrict__ out) {
    __shared__ float gv[H], hid[H], lg[DOUT];
    int gr = blockIdx.x, f = threadIdx.x;
    int cnt = gstart[gr + 1] - gstart[gr];
    gv[f] = gsum[gr * H + f] / fmaxf((float)cnt, 1.f);
    __syncthreads();
    float acc = fb1[f];
    for (int k = 0; k < H; ++k) acc = fmaf(gv[k], fW1[k * H + f], acc);
    hid[f] = fmaxf(acc, 0.f);
    __syncthreads();
    if (f < DOUT) {
        float a = fb2[f];
        for (int k = 0; k < H; ++k) a = fmaf(hid[k], fW2[k * DOUT + f], a);
        lg[f] = a;
    }
    __syncthreads();
    if (f < DOUT) {
        float mx = -1e30f;
        for (int j = 0; j < DOUT; ++j) mx = fmaxf(mx, lg[j]);
        float ssum = 0.f;
        for (int j = 0; j < DOUT; ++j) ssum += expf(lg[j] - mx);
        out[gr * DOUT + f] = expf(lg[f] - mx) / ssum;
    }
}

// ---------------- launch ----------------

extern "C" void kernel_launch(void* const* d_in, const int* in_sizes, int n_in,
                              void* d_out, int out_size, void* d_ws, size_t ws_size,
                              hipStream_t stream) {
    const float* x = (const float*)d_in[0];
    const int* edge = (const int*)d_in[1];
    const int* batch = (const int*)d_in[2];
    const float* W1 = (const float*)d_in[3];
    const float* b1 = (const float*)d_in[4];
    const float* W2 = (const float*)d_in[5];
    const float* b2 = (const float*)d_in[6];
    const float* fW1 = (const float*)d_in[7];
    const float* fb1 = (const float*)d_in[8];
    const float* fW2 = (const float*)d_in[9];
    const float* fb2 = (const float*)d_in[10];
    float* out = (float*)d_out;

    int N = in_sizes[0] / H;
    int E = in_sizes[1] / 2;
    const int* srcI = edge;
    const int* dstI = edge + E;

    char* ws = (char*)d_ws;
    size_t off = 0;
    auto alloc = [&](size_t bytes) {
        void* p = ws + off;
        off = (off + bytes + 255) & ~(size_t)255;
        return p;
    };
    int* deg = (int*)alloc((size_t)N * 4);
    int* row_ptr = (int*)alloc((size_t)(N + 1) * 4);
    int* fill = (int*)alloc((size_t)N * 4);
    int* col = (int*)alloc((size_t)E * 4);
    float* dinv = (float*)alloc((size_t)N * 4);
    int* bsum = (int*)alloc(4096);
    int* gstart = (int*)alloc(512);
    int* bcnt = (int*)alloc(NBUCK_MAX * 4);
    int* bfill = (int*)alloc(NBUCK_MAX * 4);
    unsigned int* Wbf1 = (unsigned int*)alloc(128 * 64 * 4);
    unsigned int* Wbf2 = (unsigned int*)alloc(128 * 64 * 4);
    float* gsum = (float*)alloc((size_t)NGRAPH * H * 4);
    // A region: holds es (E*8B) during CSR build, then bf16 activations (N*H*2B)
    unsigned short* Abf = (unsigned short*)alloc((size_t)N * H * 4);
    unsigned int* Bbf = (unsigned int*)alloc((size_t)N * H * 4);
    (void)ws_size;

    int2* es = (int2*)Abf;  // consumed before mm overwrites; same stream

    int bshift = 0;
    while (((N - 1) >> bshift) >= NBUCK_MAX) ++bshift;
    int nbuck = ((N - 1) >> bshift) + 1;

    hipMemsetAsync(deg, 0, (size_t)N * 4, stream);
    hipMemsetAsync(bcnt, 0, NBUCK_MAX * 4, stream);
    hipMemsetAsync(gsum, 0, (size_t)NGRAPH * H * 4, stream);

    int nb = (N + 1023) / 1024;
    int nst = (E + SORT_TILE - 1) / SORT_TILE;

    prep_w_kernel<<<64, 256, 0, stream>>>(W1, W2, Wbf1, Wbf2);

    bucket_hist_kernel<<<nst, 256, 0, stream>>>(dstI, E, bshift, bcnt);
    bucket_scan_kernel<<<1, 1, 0, stream>>>(bcnt, bfill, nbuck);
    bucket_scatter_kernel<<<nst, 256, 0, stream>>>(srcI, dstI, E, bshift, bfill, es);
    deg_hist_sorted<<<(E + 255) / 256, 256, 0, stream>>>(es, E, deg);

    batch_bounds_kernel<<<(N + 255) / 256, 256, 0, stream>>>(batch, N, gstart);
    scan_phase1<<<nb, 256, 0, stream>>>(deg, N, bsum);
    scan_phase2<<<1, 1, 0, stream>>>(bsum, nb, row_ptr, N, E);
    scan_phase3<<<nb, 256, 0, stream>>>(deg, bsum, N, row_ptr, fill, dinv);
    fill_csr_sorted<<<(E + 255) / 256, 256, 0, stream>>>(es, E, fill, col);

    int mmblocks = (N + 127) / 128;
    int aggblocks = 8 * ((N + AGG_ROWS - 1) / AGG_ROWS);
    mm_mfma_kernel<0><<<mmblocks, 256, 0, stream>>>(x, Wbf1, dinv, Abf, N);
    agg_bf16_sliced<<<aggblocks, 256, 0, stream>>>((const unsigned int*)Abf, row_ptr, col,
                                                   dinv, b1, Bbf, N);
    mm_mfma_kernel<1><<<mmblocks, 256, 0, stream>>>(Bbf, Wbf2, dinv, Abf, N);
    agg_bf16_sliced<<<aggblocks, 256, 0, stream>>>((const unsigned int*)Abf, row_ptr, col,
                                                   dinv, b2, Bbf, N);
    pool_partial<<<(N + PCHUNK - 1) / PCHUNK, 64, 0, stream>>>(Bbf, batch, gsum, N);
    head_kernel<<<NGRAPH, 128, 0, stream>>>(gsum, gstart, fW1, fb1, fW2, fb2, out);
}

// Round 11
// 283.675 us; speedup vs baseline: 2.2661x; 2.2661x over previous
//
#include <hip/hip_runtime.h>
#include <hip/hip_bf16.h>

#define H 128
#define DOUT 32
#define NGRAPH 64
#define PCHUNK 128
#define SORT_TILE 4096
#define NBUCK_MAX 128
#define BNODES 1024  // nodes per bucket (bshift=10 for N=100000)

typedef __attribute__((ext_vector_type(8))) short bf16x8;
typedef __attribute__((ext_vector_type(4))) float f32x4;
union U4B {
    uint4 u;
    bf16x8 b;
};

// bf16 helpers (RTN-even pack, bit-shift unpack)
static __device__ __forceinline__ unsigned short f2bf(float v) {
    unsigned int u = __float_as_uint(v);
    unsigned int r = (u + 0x7FFFu + ((u >> 16) & 1u)) >> 16;
    return (unsigned short)r;
}
#define BFLO(w) __uint_as_float((w) << 16)
#define BFHI(w) __uint_as_float((w) & 0xFFFF0000u)

// ---------------- setup: zero counters + prep_w + batch_bounds (1 dispatch) -----

__global__ __launch_bounds__(256) void setup_kernel(const int* __restrict__ batch, int N,
                                                    int* __restrict__ gstart,
                                                    const float* __restrict__ W1,
                                                    const float* __restrict__ W2,
                                                    unsigned int* __restrict__ Wbf1,
                                                    unsigned int* __restrict__ Wbf2,
                                                    int* __restrict__ bcnt,
                                                    int* __restrict__ tick,
                                                    float* __restrict__ gsum) {
    int b = blockIdx.x, t = threadIdx.x;
    if (b == 0) {
        if (t < NBUCK_MAX) bcnt[t] = 0;
        if (t == 0) *tick = 0;
        for (int j = t; j < NGRAPH * H; j += 256) gsum[j] = 0.f;
        return;
    }
    if (b <= 64) {
        int pb = b - 1;
        const float* W = (pb < 32) ? W1 : W2;
        unsigned int* Wbf = (pb < 32) ? Wbf1 : Wbf2;
        int q = (pb & 31) * 256 + t;  // 0..8191
        int colq = q >> 6, j = q & 63;
        int p = j >> 2, wI = j & 3;
        int cq = p ^ (colq & 15);
        int k0 = 8 * cq + 2 * wI;
        Wbf[q] = (unsigned int)f2bf(W[k0 * H + colq]) |
                 ((unsigned int)f2bf(W[(k0 + 1) * H + colq]) << 16);
        return;
    }
    int i = (b - 65) * 256 + t;
    if (i < N) {
        int bb = batch[i];
        int bp = (i == 0) ? -1 : batch[i - 1];
        for (int g = bp + 1; g <= bb; ++g) gstart[g] = i;
        if (i == N - 1)
            for (int g = bb + 1; g <= NGRAPH; ++g) gstart[g] = N;
    }
}

// ---------------- bucket hist + fused last-block scan ----------------

__global__ __launch_bounds__(256) void bucket_hist_kernel(const int* __restrict__ dst, int E,
                                                          int bshift, int nbuck,
                                                          int* __restrict__ bcnt,
                                                          int* __restrict__ tick,
                                                          int* __restrict__ bstart,
                                                          int* __restrict__ bfill) {
    __shared__ int lh[NBUCK_MAX];
    __shared__ int done;
    __shared__ int scnt[NBUCK_MAX];
    int t = threadIdx.x;
    if (t < NBUCK_MAX) lh[t] = 0;
    __syncthreads();
    int base = blockIdx.x * SORT_TILE;
    int cnt = E - base;
    if (cnt > SORT_TILE) cnt = SORT_TILE;
    for (int j = t; j < cnt; j += 256) atomicAdd(&lh[dst[base + j] >> bshift], 1);
    __syncthreads();
    if (t < NBUCK_MAX && lh[t]) atomicAdd(&bcnt[t], lh[t]);
    __syncthreads();
    if (t == 0) {
        __threadfence();
        done = (atomicAdd(tick, 1) == (int)gridDim.x - 1) ? 1 : 0;
    }
    __syncthreads();
    if (done) {
        if (t < nbuck) scnt[t] = atomicAdd(&bcnt[t], 0);  // coherent read
        __syncthreads();
        if (t == 0) {
            int run = 0;
            for (int b = 0; b < nbuck; ++b) {
                bstart[b] = run;
                bfill[b] = run;
                run += scnt[b];
            }
            bstart[nbuck] = run;  // == E
        }
    }
}

// ---------------- scatter (perm-based, low LDS) ----------------

__global__ __launch_bounds__(256) void bucket_scatter_kernel(const int* __restrict__ src,
                                                             const int* __restrict__ dst, int E,
                                                             int bshift, int* __restrict__ bfill,
                                                             int2* __restrict__ es) {
    __shared__ int lh[NBUCK_MAX], lsc[NBUCK_MAX], lbase[NBUCK_MAX], lfill[NBUCK_MAX],
        ldelta[NBUCK_MAX];
    __shared__ unsigned short perm[SORT_TILE];  // slot -> tile-local index
    int t = threadIdx.x;
    if (t < NBUCK_MAX) {
        lh[t] = 0;
        lfill[t] = 0;
    }
    __syncthreads();
    int base = blockIdx.x * SORT_TILE;
    int cnt = E - base;
    if (cnt > SORT_TILE) cnt = SORT_TILE;
    for (int j = t; j < cnt; j += 256) atomicAdd(&lh[dst[base + j] >> bshift], 1);
    __syncthreads();
    if (t < NBUCK_MAX) lsc[t] = lh[t];
    __syncthreads();
    for (int off = 1; off < NBUCK_MAX; off <<= 1) {
        int x = 0;
        if (t < NBUCK_MAX && t >= off) x = lsc[t - off];
        __syncthreads();
        if (t < NBUCK_MAX) lsc[t] += x;
        __syncthreads();
    }
    if (t < NBUCK_MAX) {
        lbase[t] = lsc[t] - lh[t];
        if (lh[t] > 0) ldelta[t] = atomicAdd(&bfill[t], lh[t]) - lbase[t];
    }
    __syncthreads();
    for (int j = t; j < cnt; j += 256) {
        int b = dst[base + j] >> bshift;  // L1-resident re-read
        int r = atomicAdd(&lfill[b], 1);
        perm[lbase[b] + r] = (unsigned short)j;
    }
    __syncthreads();
    for (int s = t; s < cnt; s += 256) {
        int o = perm[s];
        int d = dst[base + o];  // L1/L2-resident re-read
        int b = d >> bshift;
        es[ldelta[b] + s] = make_int2(src[base + o], d);
    }
}

// ---------------- per-bucket counting sort: emits col, row_ptr, dinv ----------
// One block (1024 threads) per bucket. Replaces deg_hist + scan1/2/3 + fill_csr.
__global__ __launch_bounds__(1024) void bucket_sort2_kernel(const int2* __restrict__ es,
                                                            const int* __restrict__ bstart,
                                                            int bshift, int nbuck, int N, int E,
                                                            int* __restrict__ col,
                                                            int* __restrict__ row_ptr,
                                                            float* __restrict__ dinv) {
    __shared__ int cnt[BNODES];
    __shared__ int sc[BNODES];
    int b = blockIdx.x, t = threadIdx.x;
    int nodebase = b << bshift;
    int nodes_here = N - nodebase;
    if (nodes_here > BNODES) nodes_here = BNODES;
    int s = bstart[b], e = bstart[b + 1];
    cnt[t] = 0;
    __syncthreads();
    for (int j = s + t; j < e; j += 1024) atomicAdd(&cnt[es[j].y - nodebase], 1);
    __syncthreads();
    sc[t] = cnt[t];
    __syncthreads();
    for (int off = 1; off < BNODES; off <<= 1) {
        int x = (t >= off) ? sc[t - off] : 0;
        __syncthreads();
        sc[t] += x;
        __syncthreads();
    }
    // exclusive base for node t (in place)
    int excl = sc[t] - cnt[t];
    __syncthreads();
    sc[t] = excl;
    if (t < nodes_here) {
        row_ptr[nodebase + t] = s + excl;
        dinv[nodebase + t] = rsqrtf(1.0f + (float)cnt[t]);
    }
    if (b == nbuck - 1 && t == 0) row_ptr[N] = E;
    __syncthreads();
    for (int j = s + t; j < e; j += 1024) {
        int2 p = es[j];
        int local = p.y - nodebase;
        int pos = s + atomicAdd(&sc[local], 1);
        col[pos] = p.x;
    }
}

// ---------------- MFMA matmul ----------------
template <int IN_BF16>
__global__ __launch_bounds__(256) void mm_mfma_kernel(const void* __restrict__ Xv,
                                                      const unsigned int* __restrict__ Wbf,
                                                      const float* __restrict__ dinv,
                                                      unsigned short* __restrict__ Out, int M) {
    __shared__ unsigned int wlds[128 * 64];
    int t = threadIdx.x;
    const uint4* Wv = (const uint4*)Wbf;
#pragma unroll
    for (int it = 0; it < 8; ++it)
        ((uint4*)wlds)[t + it * 256] = Wv[t + it * 256];
    __syncthreads();

    int wv = t >> 6, l = t & 63;
    int l16 = l & 15, lk = l >> 4;
    int rowbase = blockIdx.x * 128 + wv * 32;

    f32x4 acc[2][8];
#pragma unroll
    for (int rt = 0; rt < 2; ++rt)
#pragma unroll
        for (int nt = 0; nt < 8; ++nt) acc[rt][nt] = (f32x4){0.f, 0.f, 0.f, 0.f};

#pragma unroll
    for (int ks = 0; ks < 4; ++ks) {
        U4B afr[2];
#pragma unroll
        for (int rt = 0; rt < 2; ++rt) {
            int row = rowbase + rt * 16 + l16;
            if (IN_BF16) {
                uint4 v = make_uint4(0u, 0u, 0u, 0u);
                if (row < M) v = *((const uint4*)Xv + (size_t)row * 16 + 4 * ks + lk);
                afr[rt].u = v;
            } else {
                const float* X = (const float*)Xv;
                float4 v0 = make_float4(0.f, 0.f, 0.f, 0.f), v1 = v0;
                if (row < M) {
                    v0 = *reinterpret_cast<const float4*>(X + (size_t)row * H + 32 * ks +
                                                          8 * lk);
                    v1 = *reinterpret_cast<const float4*>(X + (size_t)row * H + 32 * ks +
                                                          8 * lk + 4);
                }
                afr[rt].u.x = (unsigned int)f2bf(v0.x) | ((unsigned int)f2bf(v0.y) << 16);
                afr[rt].u.y = (unsigned int)f2bf(v0.z) | ((unsigned int)f2bf(v0.w) << 16);
                afr[rt].u.z = (unsigned int)f2bf(v1.x) | ((unsigned int)f2bf(v1.y) << 16);
                afr[rt].u.w = (unsigned int)f2bf(v1.z) | ((unsigned int)f2bf(v1.w) << 16);
            }
        }
#pragma unroll
        for (int nt = 0; nt < 8; ++nt) {
            int colB = nt * 16 + l16;
            int c = 4 * ks + lk;
            int p = c ^ (colB & 15);
            U4B bfr;
            bfr.u = *reinterpret_cast<const uint4*>(&wlds[colB * 64 + p * 4]);
            acc[0][nt] = __builtin_amdgcn_mfma_f32_16x16x32_bf16(afr[0].b, bfr.b, acc[0][nt],
                                                                 0, 0, 0);
            acc[1][nt] = __builtin_amdgcn_mfma_f32_16x16x32_bf16(afr[1].b, bfr.b, acc[1][nt],
                                                                 0, 0, 0);
        }
    }

#pragma unroll
    for (int rt = 0; rt < 2; ++rt) {
#pragma unroll
        for (int r = 0; r < 4; ++r) {
            int row = rowbase + rt * 16 + lk * 4 + r;
            if (row < M) {
                float dsc = dinv[row];
#pragma unroll
                for (int nt = 0; nt < 8; ++nt)
                    Out[(size_t)row * H + nt * 16 + l16] = f2bf(acc[rt][nt][r] * dsc);
            }
        }
    }
}

// ---------------- aggregation (one wave per dst row, 16-deep gather MLP) -------

__global__ __launch_bounds__(256) void agg_bf16_kernel(
    const unsigned int* __restrict__ Au, const int* __restrict__ row_ptr,
    const int* __restrict__ col, const float* __restrict__ dinv,
    const float* __restrict__ bias, unsigned int* __restrict__ OutBf, int N) {
    int wave = threadIdx.x >> 6;
    int lane = threadIdx.x & 63;
    int i = blockIdx.x * 4 + wave;
    if (i >= N) return;
    int s = row_ptr[i], e = row_ptr[i + 1];
    unsigned int ws = Au[(size_t)i * 64 + lane];  // self-loop term
    float acc0 = BFLO(ws), acc1 = BFHI(ws);
    int j = s;
    for (; j + 16 <= e; j += 16) {
        unsigned int w[16];
#pragma unroll
        for (int q = 0; q < 16; ++q) w[q] = Au[(size_t)col[j + q] * 64 + lane];
#pragma unroll
        for (int q = 0; q < 16; q += 2) {
            acc0 += BFLO(w[q]) + BFLO(w[q + 1]);
            acc1 += BFHI(w[q]) + BFHI(w[q + 1]);
        }
    }
    for (; j + 4 <= e; j += 4) {
        int c0 = col[j], c1 = col[j + 1], c2 = col[j + 2], c3 = col[j + 3];
        unsigned int w0 = Au[(size_t)c0 * 64 + lane];
        unsigned int w1 = Au[(size_t)c1 * 64 + lane];
        unsigned int w2 = Au[(size_t)c2 * 64 + lane];
        unsigned int w3 = Au[(size_t)c3 * 64 + lane];
        acc0 += BFLO(w0) + BFLO(w1);
        acc1 += BFHI(w0) + BFHI(w1);
        acc0 += BFLO(w2) + BFLO(w3);
        acc1 += BFHI(w2) + BFHI(w3);
    }
    for (; j < e; ++j) {
        unsigned int w = Au[(size_t)col[j] * 64 + lane];
        acc0 += BFLO(w);
        acc1 += BFHI(w);
    }
    float d = dinv[i];
    float o0 = fmaxf(fmaf(d, acc0, bias[2 * lane]), 0.f);
    float o1 = fmaxf(fmaf(d, acc1, bias[2 * lane + 1]), 0.f);
    OutBf[(size_t)i * 64 + lane] = (unsigned int)f2bf(o0) | ((unsigned int)f2bf(o1) << 16);
}

// ---------------- pooling (bf16 input, register pre-reduction) ----------------

__global__ __launch_bounds__(64) void pool_partial(const unsigned int* __restrict__ Bu,
                                                   const int* __restrict__ batch,
                                                   float* __restrict__ gsum, int N) {
    __shared__ int sb[PCHUNK];
    int base = blockIdx.x * PCHUNK;
    int n_here = N - base;
    if (n_here > PCHUNK) n_here = PCHUNK;
    int f = threadIdx.x;  // u32 feature-pair index 0..63
    for (int j = f; j < n_here; j += 64) sb[j] = batch[base + j];
    __syncthreads();
    float acc0 = 0.f, acc1 = 0.f;
    int cur = sb[0];
    for (int j = 0; j < n_here; ++j) {
        int g = sb[j];  // wave-uniform
        if (g != cur) {
            atomicAdd(&gsum[cur * H + 2 * f], acc0);
            atomicAdd(&gsum[cur * H + 2 * f + 1], acc1);
            acc0 = 0.f;
            acc1 = 0.f;
            cur = g;
        }
        unsigned int w = Bu[(size_t)(base + j) * 64 + f];
        acc0 += BFLO(w);
        acc1 += BFHI(w);
    }
    atomicAdd(&gsum[cur * H + 2 * f], acc0);
    atomicAdd(&gsum[cur * H + 2 * f + 1], acc1);
}

// head + pool_final fused: gv = gsum/cnt
__global__ __launch_bounds__(128) void head_kernel(const float* __restrict__ gsum,
                                                   const int* __restrict__ gstart,
                                                   const float* __restrict__ fW1,
                                                   const float* __restrict__ fb1,
                                                   const float* __restrict__ fW2,
                                                   const float* __restrict__ fb2,
                                                   float* __restrict__ out) {
    __shared__ float gv[H], hid[H], lg[DOUT];
    int gr = blockIdx.x, f = threadIdx.x;
    int cnt = gstart[gr + 1] - gstart[gr];
    gv[f] = gsum[gr * H + f] / fmaxf((float)cnt, 1.f);
    __syncthreads();
    float acc = fb1[f];
    for (int k = 0; k < H; ++k) acc = fmaf(gv[k], fW1[k * H + f], acc);
    hid[f] = fmaxf(acc, 0.f);
    __syncthreads();
    if (f < DOUT) {
        float a = fb2[f];
        for (int k = 0; k < H; ++k) a = fmaf(hid[k], fW2[k * DOUT + f], a);
        lg[f] = a;
    }
    __syncthreads();
    if (f < DOUT) {
        float mx = -1e30f;
        for (int j = 0; j < DOUT; ++j) mx = fmaxf(mx, lg[j]);
        float ssum = 0.f;
        for (int j = 0; j < DOUT; ++j) ssum += expf(lg[j] - mx);
        out[gr * DOUT + f] = expf(lg[f] - mx) / ssum;
    }
}

// ---------------- launch ----------------

extern "C" void kernel_launch(void* const* d_in, const int* in_sizes, int n_in,
                              void* d_out, int out_size, void* d_ws, size_t ws_size,
                              hipStream_t stream) {
    const float* x = (const float*)d_in[0];
    const int* edge = (const int*)d_in[1];
    const int* batch = (const int*)d_in[2];
    const float* W1 = (const float*)d_in[3];
    const float* b1 = (const float*)d_in[4];
    const float* W2 = (const float*)d_in[5];
    const float* b2 = (const float*)d_in[6];
    const float* fW1 = (const float*)d_in[7];
    const float* fb1 = (const float*)d_in[8];
    const float* fW2 = (const float*)d_in[9];
    const float* fb2 = (const float*)d_in[10];
    float* out = (float*)d_out;

    int N = in_sizes[0] / H;
    int E = in_sizes[1] / 2;
    const int* srcI = edge;
    const int* dstI = edge + E;

    char* ws = (char*)d_ws;
    size_t off = 0;
    auto alloc = [&](size_t bytes) {
        void* p = ws + off;
        off = (off + bytes + 255) & ~(size_t)255;
        return p;
    };
    int* row_ptr = (int*)alloc((size_t)(N + 1) * 4);
    int* col = (int*)alloc((size_t)E * 4);
    float* dinv = (float*)alloc((size_t)N * 4);
    int* gstart = (int*)alloc(512);
    int* bcnt = (int*)alloc(NBUCK_MAX * 4);
    int* bstart = (int*)alloc((NBUCK_MAX + 1) * 4);
    int* bfill = (int*)alloc(NBUCK_MAX * 4);
    int* tick = (int*)alloc(256);
    unsigned int* Wbf1 = (unsigned int*)alloc(128 * 64 * 4);
    unsigned int* Wbf2 = (unsigned int*)alloc(128 * 64 * 4);
    float* gsum = (float*)alloc((size_t)NGRAPH * H * 4);
    // A region: holds es (E*8B) during CSR build, then bf16 activations (N*H*2B)
    unsigned short* Abf = (unsigned short*)alloc((size_t)N * H * 4);
    unsigned int* Bbf = (unsigned int*)alloc((size_t)N * H * 4);
    (void)ws_size;

    int2* es = (int2*)Abf;  // consumed by bucket_sort2 before mm1 overwrites

    int bshift = 0;
    while (((N - 1) >> bshift) >= NBUCK_MAX) ++bshift;
    int nbuck = ((N - 1) >> bshift) + 1;

    int nst = (E + SORT_TILE - 1) / SORT_TILE;
    int nbb = (N + 255) / 256;

    setup_kernel<<<65 + nbb, 256, 0, stream>>>(batch, N, gstart, W1, W2, Wbf1, Wbf2, bcnt,
                                               tick, gsum);
    bucket_hist_kernel<<<nst, 256, 0, stream>>>(dstI, E, bshift, nbuck, bcnt, tick, bstart,
                                                bfill);
    bucket_scatter_kernel<<<nst, 256, 0, stream>>>(srcI, dstI, E, bshift, bfill, es);
    bucket_sort2_kernel<<<nbuck, 1024, 0, stream>>>(es, bstart, bshift, nbuck, N, E, col,
                                                    row_ptr, dinv);

    int mmblocks = (N + 127) / 128;
    int aggblocks = (N + 3) / 4;
    mm_mfma_kernel<0><<<mmblocks, 256, 0, stream>>>(x, Wbf1, dinv, Abf, N);
    agg_bf16_kernel<<<aggblocks, 256, 0, stream>>>((const unsigned int*)Abf, row_ptr, col,
                                                   dinv, b1, Bbf, N);
    mm_mfma_kernel<1><<<mmblocks, 256, 0, stream>>>(Bbf, Wbf2, dinv, Abf, N);
    agg_bf16_kernel<<<aggblocks, 256, 0, stream>>>((const unsigned int*)Abf, row_ptr, col,
                                                   dinv, b2, Bbf, N);
    pool_partial<<<(N + PCHUNK - 1) / PCHUNK, 64, 0, stream>>>(Bbf, batch, gsum, N);
    head_kernel<<<NGRAPH, 128, 0, stream>>>(gsum, gstart, fW1, fb1, fW2, fb2, out);
}

// Round 12
// 278.379 us; speedup vs baseline: 2.3092x; 1.0190x over previous
//
#include <hip/hip_runtime.h>
#include <hip/hip_bf16.h>

#define H 128
#define DOUT 32
#define NGRAPH 64
#define PCHUNK 128
#define SORT_TILE 4096
#define NBUCK_MAX 128
#define BNODES 1024  // nodes per bucket (bshift=10 for N=100000)

typedef __attribute__((ext_vector_type(8))) short bf16x8;
typedef __attribute__((ext_vector_type(4))) float f32x4;
union U4B {
    uint4 u;
    bf16x8 b;
};

// bf16 helpers (RTN-even pack, bit-shift unpack)
static __device__ __forceinline__ unsigned short f2bf(float v) {
    unsigned int u = __float_as_uint(v);
    unsigned int r = (u + 0x7FFFu + ((u >> 16) & 1u)) >> 16;
    return (unsigned short)r;
}
#define BFLO(w) __uint_as_float((w) << 16)
#define BFHI(w) __uint_as_float((w) & 0xFFFF0000u)

// ---------------- setup: gsum zero + prep_w + batch_bounds + bucket hist -------
// Block roles: [0]=gsum zero; [1,64]=W prep; [65,64+nbb]=batch bounds;
// [65+nbb, 64+nbb+nst]=edge-bucket histogram tiles (+ ticket last-block scan).
// bcnt/tick are pre-zeroed by a memset before this kernel.
__global__ __launch_bounds__(256) void setup_kernel(
    const int* __restrict__ batch, int N, int* __restrict__ gstart,
    const float* __restrict__ W1, const float* __restrict__ W2,
    unsigned int* __restrict__ Wbf1, unsigned int* __restrict__ Wbf2,
    float* __restrict__ gsum, const int* __restrict__ dst, int E, int bshift, int nbuck,
    int nbb, int nst, int* __restrict__ bcnt, int* __restrict__ tick,
    int* __restrict__ bstart, int* __restrict__ bfill) {
    int b = blockIdx.x, t = threadIdx.x;
    if (b == 0) {
        for (int j = t; j < NGRAPH * H; j += 256) gsum[j] = 0.f;
        return;
    }
    if (b <= 64) {
        int pb = b - 1;
        const float* W = (pb < 32) ? W1 : W2;
        unsigned int* Wbf = (pb < 32) ? Wbf1 : Wbf2;
        int q = (pb & 31) * 256 + t;  // 0..8191
        int colq = q >> 6, j = q & 63;
        int p = j >> 2, wI = j & 3;
        int cq = p ^ (colq & 15);
        int k0 = 8 * cq + 2 * wI;
        Wbf[q] = (unsigned int)f2bf(W[k0 * H + colq]) |
                 ((unsigned int)f2bf(W[(k0 + 1) * H + colq]) << 16);
        return;
    }
    if (b <= 64 + nbb) {
        int i = (b - 65) * 256 + t;
        if (i < N) {
            int bb = batch[i];
            int bp = (i == 0) ? -1 : batch[i - 1];
            for (int g = bp + 1; g <= bb; ++g) gstart[g] = i;
            if (i == N - 1)
                for (int g = bb + 1; g <= NGRAPH; ++g) gstart[g] = N;
        }
        return;
    }
    // ---- histogram tile ----
    __shared__ int lh[NBUCK_MAX];
    __shared__ int done;
    __shared__ int scnt[NBUCK_MAX];
    int tile = b - 65 - nbb;
    if (t < NBUCK_MAX) lh[t] = 0;
    __syncthreads();
    int base = tile * SORT_TILE;
    int cnt = E - base;
    if (cnt > SORT_TILE) cnt = SORT_TILE;
    for (int j = t; j < cnt; j += 256) atomicAdd(&lh[dst[base + j] >> bshift], 1);
    __syncthreads();
    if (t < NBUCK_MAX && lh[t]) atomicAdd(&bcnt[t], lh[t]);
    __syncthreads();
    if (t == 0) {
        __threadfence();
        done = (atomicAdd(tick, 1) == nst - 1) ? 1 : 0;
    }
    __syncthreads();
    if (done) {
        if (t < nbuck) scnt[t] = atomicAdd(&bcnt[t], 0);  // coherent read
        __syncthreads();
        if (t == 0) {
            int run = 0;
            for (int k = 0; k < nbuck; ++k) {
                bstart[k] = run;
                bfill[k] = run;
                run += scnt[k];
            }
            bstart[nbuck] = run;  // == E
        }
    }
}

// ---------------- scatter (packed u32 es, direct LDS staging) ----------------
// es entry = (src << bshift) | (dst & mask); bucket recoverable from position.
__global__ __launch_bounds__(256) void bucket_scatter_kernel(const int* __restrict__ src,
                                                             const int* __restrict__ dst, int E,
                                                             int bshift, int* __restrict__ bfill,
                                                             unsigned int* __restrict__ es) {
    __shared__ int lh[NBUCK_MAX], lsc[NBUCK_MAX], lbase[NBUCK_MAX], lfill[NBUCK_MAX],
        ldelta[NBUCK_MAX];
    __shared__ unsigned int pk[SORT_TILE];
    __shared__ unsigned char sb[SORT_TILE];
    int t = threadIdx.x;
    unsigned int mask = (1u << bshift) - 1u;
    if (t < NBUCK_MAX) {
        lh[t] = 0;
        lfill[t] = 0;
    }
    __syncthreads();
    int base = blockIdx.x * SORT_TILE;
    int cnt = E - base;
    if (cnt > SORT_TILE) cnt = SORT_TILE;
    for (int j = t; j < cnt; j += 256) atomicAdd(&lh[dst[base + j] >> bshift], 1);
    __syncthreads();
    if (t < NBUCK_MAX) lsc[t] = lh[t];
    __syncthreads();
    for (int off = 1; off < NBUCK_MAX; off <<= 1) {
        int x = 0;
        if (t < NBUCK_MAX && t >= off) x = lsc[t - off];
        __syncthreads();
        if (t < NBUCK_MAX) lsc[t] += x;
        __syncthreads();
    }
    if (t < NBUCK_MAX) {
        lbase[t] = lsc[t] - lh[t];
        if (lh[t] > 0) ldelta[t] = atomicAdd(&bfill[t], lh[t]) - lbase[t];
    }
    __syncthreads();
    for (int j = t; j < cnt; j += 256) {
        int d = dst[base + j];
        int b = d >> bshift;
        int r = atomicAdd(&lfill[b], 1);
        int slot = lbase[b] + r;
        pk[slot] = ((unsigned int)src[base + j] << bshift) | ((unsigned int)d & mask);
        sb[slot] = (unsigned char)b;
    }
    __syncthreads();
    for (int s = t; s < cnt; s += 256) {
        es[ldelta[sb[s]] + s] = pk[s];
    }
}

// ---------------- per-bucket counting sort: emits col, row_ptr, dinv ----------
__global__ __launch_bounds__(1024) void bucket_sort2_kernel(const unsigned int* __restrict__ es,
                                                            const int* __restrict__ bstart,
                                                            int bshift, int nbuck, int N, int E,
                                                            int* __restrict__ col,
                                                            int* __restrict__ row_ptr,
                                                            float* __restrict__ dinv) {
    __shared__ int cnt[BNODES];
    __shared__ int sc[BNODES];
    int b = blockIdx.x, t = threadIdx.x;
    unsigned int mask = (1u << bshift) - 1u;
    int nodebase = b << bshift;
    int nodes_here = N - nodebase;
    if (nodes_here > BNODES) nodes_here = BNODES;
    int s = bstart[b], e = bstart[b + 1];
    cnt[t] = 0;
    __syncthreads();
    for (int j = s + t; j < e; j += 1024) atomicAdd(&cnt[es[j] & mask], 1);
    __syncthreads();
    sc[t] = cnt[t];
    __syncthreads();
    for (int off = 1; off < BNODES; off <<= 1) {
        int x = (t >= off) ? sc[t - off] : 0;
        __syncthreads();
        sc[t] += x;
        __syncthreads();
    }
    int excl = sc[t] - cnt[t];
    __syncthreads();
    sc[t] = excl;
    if (t < nodes_here) {
        row_ptr[nodebase + t] = s + excl;
        dinv[nodebase + t] = rsqrtf(1.0f + (float)cnt[t]);
    }
    if (b == nbuck - 1 && t == 0) row_ptr[N] = E;
    __syncthreads();
    for (int j = s + t; j < e; j += 1024) {
        unsigned int p = es[j];
        int local = p & mask;
        int pos = s + atomicAdd(&sc[local], 1);
        col[pos] = (int)(p >> bshift);
    }
}

// ---------------- MFMA matmul ----------------
template <int IN_BF16>
__global__ __launch_bounds__(256) void mm_mfma_kernel(const void* __restrict__ Xv,
                                                      const unsigned int* __restrict__ Wbf,
                                                      const float* __restrict__ dinv,
                                                      unsigned short* __restrict__ Out, int M) {
    __shared__ unsigned int wlds[128 * 64];
    int t = threadIdx.x;
    const uint4* Wv = (const uint4*)Wbf;
#pragma unroll
    for (int it = 0; it < 8; ++it)
        ((uint4*)wlds)[t + it * 256] = Wv[t + it * 256];
    __syncthreads();

    int wv = t >> 6, l = t & 63;
    int l16 = l & 15, lk = l >> 4;
    int rowbase = blockIdx.x * 128 + wv * 32;

    f32x4 acc[2][8];
#pragma unroll
    for (int rt = 0; rt < 2; ++rt)
#pragma unroll
        for (int nt = 0; nt < 8; ++nt) acc[rt][nt] = (f32x4){0.f, 0.f, 0.f, 0.f};

#pragma unroll
    for (int ks = 0; ks < 4; ++ks) {
        U4B afr[2];
#pragma unroll
        for (int rt = 0; rt < 2; ++rt) {
            int row = rowbase + rt * 16 + l16;
            if (IN_BF16) {
                uint4 v = make_uint4(0u, 0u, 0u, 0u);
                if (row < M) v = *((const uint4*)Xv + (size_t)row * 16 + 4 * ks + lk);
                afr[rt].u = v;
            } else {
                const float* X = (const float*)Xv;
                float4 v0 = make_float4(0.f, 0.f, 0.f, 0.f), v1 = v0;
                if (row < M) {
                    v0 = *reinterpret_cast<const float4*>(X + (size_t)row * H + 32 * ks +
                                                          8 * lk);
                    v1 = *reinterpret_cast<const float4*>(X + (size_t)row * H + 32 * ks +
                                                          8 * lk + 4);
                }
                afr[rt].u.x = (unsigned int)f2bf(v0.x) | ((unsigned int)f2bf(v0.y) << 16);
                afr[rt].u.y = (unsigned int)f2bf(v0.z) | ((unsigned int)f2bf(v0.w) << 16);
                afr[rt].u.z = (unsigned int)f2bf(v1.x) | ((unsigned int)f2bf(v1.y) << 16);
                afr[rt].u.w = (unsigned int)f2bf(v1.z) | ((unsigned int)f2bf(v1.w) << 16);
            }
        }
#pragma unroll
        for (int nt = 0; nt < 8; ++nt) {
            int colB = nt * 16 + l16;
            int c = 4 * ks + lk;
            int p = c ^ (colB & 15);
            U4B bfr;
            bfr.u = *reinterpret_cast<const uint4*>(&wlds[colB * 64 + p * 4]);
            acc[0][nt] = __builtin_amdgcn_mfma_f32_16x16x32_bf16(afr[0].b, bfr.b, acc[0][nt],
                                                                 0, 0, 0);
            acc[1][nt] = __builtin_amdgcn_mfma_f32_16x16x32_bf16(afr[1].b, bfr.b, acc[1][nt],
                                                                 0, 0, 0);
        }
    }

#pragma unroll
    for (int rt = 0; rt < 2; ++rt) {
#pragma unroll
        for (int r = 0; r < 4; ++r) {
            int row = rowbase + rt * 16 + lk * 4 + r;
            if (row < M) {
                float dsc = dinv[row];
#pragma unroll
                for (int nt = 0; nt < 8; ++nt)
                    Out[(size_t)row * H + nt * 16 + l16] = f2bf(acc[rt][nt][r] * dsc);
            }
        }
    }
}

// ---------------- aggregation (one wave per dst row, 16-deep gather MLP) -------

__global__ __launch_bounds__(256) void agg_bf16_kernel(
    const unsigned int* __restrict__ Au, const int* __restrict__ row_ptr,
    const int* __restrict__ col, const float* __restrict__ dinv,
    const float* __restrict__ bias, unsigned int* __restrict__ OutBf, int N) {
    int wave = threadIdx.x >> 6;
    int lane = threadIdx.x & 63;
    int i = blockIdx.x * 4 + wave;
    if (i >= N) return;
    int s = row_ptr[i], e = row_ptr[i + 1];
    unsigned int ws = Au[(size_t)i * 64 + lane];  // self-loop term
    float acc0 = BFLO(ws), acc1 = BFHI(ws);
    int j = s;
    for (; j + 16 <= e; j += 16) {
        unsigned int w[16];
#pragma unroll
        for (int q = 0; q < 16; ++q) w[q] = Au[(size_t)col[j + q] * 64 + lane];
#pragma unroll
        for (int q = 0; q < 16; q += 2) {
            acc0 += BFLO(w[q]) + BFLO(w[q + 1]);
            acc1 += BFHI(w[q]) + BFHI(w[q + 1]);
        }
    }
    for (; j + 4 <= e; j += 4) {
        int c0 = col[j], c1 = col[j + 1], c2 = col[j + 2], c3 = col[j + 3];
        unsigned int w0 = Au[(size_t)c0 * 64 + lane];
        unsigned int w1 = Au[(size_t)c1 * 64 + lane];
        unsigned int w2 = Au[(size_t)c2 * 64 + lane];
        unsigned int w3 = Au[(size_t)c3 * 64 + lane];
        acc0 += BFLO(w0) + BFLO(w1);
        acc1 += BFHI(w0) + BFHI(w1);
        acc0 += BFLO(w2) + BFLO(w3);
        acc1 += BFHI(w2) + BFHI(w3);
    }
    for (; j < e; ++j) {
        unsigned int w = Au[(size_t)col[j] * 64 + lane];
        acc0 += BFLO(w);
        acc1 += BFHI(w);
    }
    float d = dinv[i];
    float o0 = fmaxf(fmaf(d, acc0, bias[2 * lane]), 0.f);
    float o1 = fmaxf(fmaf(d, acc1, bias[2 * lane + 1]), 0.f);
    OutBf[(size_t)i * 64 + lane] = (unsigned int)f2bf(o0) | ((unsigned int)f2bf(o1) << 16);
}

// ---------------- pooling (bf16 input, register pre-reduction) ----------------

__global__ __launch_bounds__(64) void pool_partial(const unsigned int* __restrict__ Bu,
                                                   const int* __restrict__ batch,
                                                   float* __restrict__ gsum, int N) {
    __shared__ int sb[PCHUNK];
    int base = blockIdx.x * PCHUNK;
    int n_here = N - base;
    if (n_here > PCHUNK) n_here = PCHUNK;
    int f = threadIdx.x;  // u32 feature-pair index 0..63
    for (int j = f; j < n_here; j += 64) sb[j] = batch[base + j];
    __syncthreads();
    float acc0 = 0.f, acc1 = 0.f;
    int cur = sb[0];
    for (int j = 0; j < n_here; ++j) {
        int g = sb[j];  // wave-uniform
        if (g != cur) {
            atomicAdd(&gsum[cur * H + 2 * f], acc0);
            atomicAdd(&gsum[cur * H + 2 * f + 1], acc1);
            acc0 = 0.f;
            acc1 = 0.f;
            cur = g;
        }
        unsigned int w = Bu[(size_t)(base + j) * 64 + f];
        acc0 += BFLO(w);
        acc1 += BFHI(w);
    }
    atomicAdd(&gsum[cur * H + 2 * f], acc0);
    atomicAdd(&gsum[cur * H + 2 * f + 1], acc1);
}

// head + pool_final fused: gv = gsum/cnt
__global__ __launch_bounds__(128) void head_kernel(const float* __restrict__ gsum,
                                                   const int* __restrict__ gstart,
                                                   const float* __restrict__ fW1,
                                                   const float* __restrict__ fb1,
                                                   const float* __restrict__ fW2,
                                                   const float* __restrict__ fb2,
                                                   float* __restrict__ out) {
    __shared__ float gv[H], hid[H], lg[DOUT];
    int gr = blockIdx.x, f = threadIdx.x;
    int cnt = gstart[gr + 1] - gstart[gr];
    gv[f] = gsum[gr * H + f] / fmaxf((float)cnt, 1.f);
    __syncthreads();
    float acc = fb1[f];
    for (int k = 0; k < H; ++k) acc = fmaf(gv[k], fW1[k * H + f], acc);
    hid[f] = fmaxf(acc, 0.f);
    __syncthreads();
    if (f < DOUT) {
        float a = fb2[f];
        for (int k = 0; k < H; ++k) a = fmaf(hid[k], fW2[k * DOUT + f], a);
        lg[f] = a;
    }
    __syncthreads();
    if (f < DOUT) {
        float mx = -1e30f;
        for (int j = 0; j < DOUT; ++j) mx = fmaxf(mx, lg[j]);
        float ssum = 0.f;
        for (int j = 0; j < DOUT; ++j) ssum += expf(lg[j] - mx);
        out[gr * DOUT + f] = expf(lg[f] - mx) / ssum;
    }
}

// ---------------- launch ----------------

extern "C" void kernel_launch(void* const* d_in, const int* in_sizes, int n_in,
                              void* d_out, int out_size, void* d_ws, size_t ws_size,
                              hipStream_t stream) {
    const float* x = (const float*)d_in[0];
    const int* edge = (const int*)d_in[1];
    const int* batch = (const int*)d_in[2];
    const float* W1 = (const float*)d_in[3];
    const float* b1 = (const float*)d_in[4];
    const float* W2 = (const float*)d_in[5];
    const float* b2 = (const float*)d_in[6];
    const float* fW1 = (const float*)d_in[7];
    const float* fb1 = (const float*)d_in[8];
    const float* fW2 = (const float*)d_in[9];
    const float* fb2 = (const float*)d_in[10];
    float* out = (float*)d_out;

    int N = in_sizes[0] / H;
    int E = in_sizes[1] / 2;
    const int* srcI = edge;
    const int* dstI = edge + E;

    char* ws = (char*)d_ws;
    size_t off = 0;
    auto alloc = [&](size_t bytes) {
        void* p = ws + off;
        off = (off + bytes + 255) & ~(size_t)255;
        return p;
    };
    int* row_ptr = (int*)alloc((size_t)(N + 1) * 4);
    int* col = (int*)alloc((size_t)E * 4);
    float* dinv = (float*)alloc((size_t)N * 4);
    int* gstart = (int*)alloc(512);
    int* bctk = (int*)alloc(192 * 4);  // bcnt[128] + tick (zeroed together)
    int* bstart = (int*)alloc((NBUCK_MAX + 1) * 4);
    int* bfill = (int*)alloc(NBUCK_MAX * 4);
    unsigned int* Wbf1 = (unsigned int*)alloc(128 * 64 * 4);
    unsigned int* Wbf2 = (unsigned int*)alloc(128 * 64 * 4);
    float* gsum = (float*)alloc((size_t)NGRAPH * H * 4);
    // A region: holds es (E*4B packed) during CSR build, then bf16 activations
    unsigned short* Abf = (unsigned short*)alloc((size_t)N * H * 4);
    unsigned int* Bbf = (unsigned int*)alloc((size_t)N * H * 4);
    (void)ws_size;

    int* bcnt = bctk;
    int* tick = bctk + 128;
    unsigned int* es = (unsigned int*)Abf;  // consumed by sort2 before mm1 writes

    int bshift = 0;
    while (((N - 1) >> bshift) >= NBUCK_MAX) ++bshift;
    int nbuck = ((N - 1) >> bshift) + 1;

    int nst = (E + SORT_TILE - 1) / SORT_TILE;
    int nbb = (N + 255) / 256;

    hipMemsetAsync(bctk, 0, 192 * 4, stream);
    setup_kernel<<<65 + nbb + nst, 256, 0, stream>>>(batch, N, gstart, W1, W2, Wbf1, Wbf2,
                                                     gsum, dstI, E, bshift, nbuck, nbb, nst,
                                                     bcnt, tick, bstart, bfill);
    bucket_scatter_kernel<<<nst, 256, 0, stream>>>(srcI, dstI, E, bshift, bfill, es);
    bucket_sort2_kernel<<<nbuck, 1024, 0, stream>>>(es, bstart, bshift, nbuck, N, E, col,
                                                    row_ptr, dinv);

    int mmblocks = (N + 127) / 128;
    int aggblocks = (N + 3) / 4;
    mm_mfma_kernel<0><<<mmblocks, 256, 0, stream>>>(x, Wbf1, dinv, Abf, N);
    agg_bf16_kernel<<<aggblocks, 256, 0, stream>>>((const unsigned int*)Abf, row_ptr, col,
                                                   dinv, b1, Bbf, N);
    mm_mfma_kernel<1><<<mmblocks, 256, 0, stream>>>(Bbf, Wbf2, dinv, Abf, N);
    agg_bf16_kernel<<<aggblocks, 256, 0, stream>>>((const unsigned int*)Abf, row_ptr, col,
                                                   dinv, b2, Bbf, N);
    pool_partial<<<(N + PCHUNK - 1) / PCHUNK, 64, 0, stream>>>(Bbf, batch, gsum, N);
    head_kernel<<<NGRAPH, 128, 0, stream>>>(gsum, gstart, fW1, fb1, fW2, fb2, out);
}

// Round 13
// 253.665 us; speedup vs baseline: 2.5342x; 1.0974x over previous
//
#include <hip/hip_runtime.h>
#include <hip/hip_bf16.h>

#define H 128
#define DOUT 32
#define NGRAPH 64
#define PCHUNK 64
#define SORT_TILE 4096
#define NBUCK_MAX 128
#define BNODES 1024  // nodes per bucket (bshift=10 for N=100000)

typedef __attribute__((ext_vector_type(8))) short bf16x8;
typedef __attribute__((ext_vector_type(4))) float f32x4;
union U4B {
    uint4 u;
    bf16x8 b;
};

// bf16 helpers (RTN-even pack, bit-shift unpack)
static __device__ __forceinline__ unsigned short f2bf(float v) {
    unsigned int u = __float_as_uint(v);
    unsigned int r = (u + 0x7FFFu + ((u >> 16) & 1u)) >> 16;
    return (unsigned short)r;
}
#define BFLO(w) __uint_as_float((w) << 16)
#define BFHI(w) __uint_as_float((w) & 0xFFFF0000u)

// ---------------- setup: gsum zero + prep_w + batch_bounds + bucket hist -------
__global__ __launch_bounds__(256) void setup_kernel(
    const int* __restrict__ batch, int N, int* __restrict__ gstart,
    const float* __restrict__ W1, const float* __restrict__ W2,
    unsigned int* __restrict__ Wbf1, unsigned int* __restrict__ Wbf2,
    float* __restrict__ gsum, const int* __restrict__ dst, int E, int bshift, int nbuck,
    int nbb, int nst, int* __restrict__ bcnt, int* __restrict__ tick,
    int* __restrict__ bstart, int* __restrict__ bfill) {
    int b = blockIdx.x, t = threadIdx.x;
    if (b == 0) {
        for (int j = t; j < NGRAPH * H; j += 256) gsum[j] = 0.f;
        return;
    }
    if (b <= 64) {
        int pb = b - 1;
        const float* W = (pb < 32) ? W1 : W2;
        unsigned int* Wbf = (pb < 32) ? Wbf1 : Wbf2;
        int q = (pb & 31) * 256 + t;  // 0..8191
        int colq = q >> 6, j = q & 63;
        int p = j >> 2, wI = j & 3;
        int cq = p ^ (colq & 15);
        int k0 = 8 * cq + 2 * wI;
        Wbf[q] = (unsigned int)f2bf(W[k0 * H + colq]) |
                 ((unsigned int)f2bf(W[(k0 + 1) * H + colq]) << 16);
        return;
    }
    if (b <= 64 + nbb) {
        int i = (b - 65) * 256 + t;
        if (i < N) {
            int bb = batch[i];
            int bp = (i == 0) ? -1 : batch[i - 1];
            for (int g = bp + 1; g <= bb; ++g) gstart[g] = i;
            if (i == N - 1)
                for (int g = bb + 1; g <= NGRAPH; ++g) gstart[g] = N;
        }
        return;
    }
    // ---- histogram tile ----
    __shared__ int lh[NBUCK_MAX];
    __shared__ int done;
    __shared__ int scnt[NBUCK_MAX];
    int tile = b - 65 - nbb;
    if (t < NBUCK_MAX) lh[t] = 0;
    __syncthreads();
    int base = tile * SORT_TILE;
    int cnt = E - base;
    if (cnt > SORT_TILE) cnt = SORT_TILE;
    for (int j = t; j < cnt; j += 256) atomicAdd(&lh[dst[base + j] >> bshift], 1);
    __syncthreads();
    if (t < NBUCK_MAX && lh[t]) atomicAdd(&bcnt[t], lh[t]);
    __syncthreads();
    if (t == 0) {
        __threadfence();
        done = (atomicAdd(tick, 1) == nst - 1) ? 1 : 0;
    }
    __syncthreads();
    if (done) {
        if (t < nbuck) scnt[t] = atomicAdd(&bcnt[t], 0);  // coherent read
        __syncthreads();
        if (t == 0) {
            int run = 0;
            for (int k = 0; k < nbuck; ++k) {
                bstart[k] = run;
                bfill[k] = run;
                run += scnt[k];
            }
            bstart[nbuck] = run;  // == E
        }
    }
}

// ---------------- scatter (packed u32 es, direct LDS staging) ----------------
__global__ __launch_bounds__(256) void bucket_scatter_kernel(const int* __restrict__ src,
                                                             const int* __restrict__ dst, int E,
                                                             int bshift, int* __restrict__ bfill,
                                                             unsigned int* __restrict__ es) {
    __shared__ int lh[NBUCK_MAX], lsc[NBUCK_MAX], lbase[NBUCK_MAX], lfill[NBUCK_MAX],
        ldelta[NBUCK_MAX];
    __shared__ unsigned int pk[SORT_TILE];
    __shared__ unsigned char sb[SORT_TILE];
    int t = threadIdx.x;
    unsigned int mask = (1u << bshift) - 1u;
    if (t < NBUCK_MAX) {
        lh[t] = 0;
        lfill[t] = 0;
    }
    __syncthreads();
    int base = blockIdx.x * SORT_TILE;
    int cnt = E - base;
    if (cnt > SORT_TILE) cnt = SORT_TILE;
    for (int j = t; j < cnt; j += 256) atomicAdd(&lh[dst[base + j] >> bshift], 1);
    __syncthreads();
    if (t < NBUCK_MAX) lsc[t] = lh[t];
    __syncthreads();
    for (int off = 1; off < NBUCK_MAX; off <<= 1) {
        int x = 0;
        if (t < NBUCK_MAX && t >= off) x = lsc[t - off];
        __syncthreads();
        if (t < NBUCK_MAX) lsc[t] += x;
        __syncthreads();
    }
    if (t < NBUCK_MAX) {
        lbase[t] = lsc[t] - lh[t];
        if (lh[t] > 0) ldelta[t] = atomicAdd(&bfill[t], lh[t]) - lbase[t];
    }
    __syncthreads();
    for (int j = t; j < cnt; j += 256) {
        int d = dst[base + j];
        int b = d >> bshift;
        int r = atomicAdd(&lfill[b], 1);
        int slot = lbase[b] + r;
        pk[slot] = ((unsigned int)src[base + j] << bshift) | ((unsigned int)d & mask);
        sb[slot] = (unsigned char)b;
    }
    __syncthreads();
    for (int s = t; s < cnt; s += 256) {
        es[ldelta[sb[s]] + s] = pk[s];
    }
}

// ---------------- per-bucket counting sort: emits col, row_ptr, dinv ----------
__global__ __launch_bounds__(1024) void bucket_sort2_kernel(const unsigned int* __restrict__ es,
                                                            const int* __restrict__ bstart,
                                                            int bshift, int nbuck, int N, int E,
                                                            int* __restrict__ col,
                                                            int* __restrict__ row_ptr,
                                                            float* __restrict__ dinv) {
    __shared__ int cnt[BNODES];
    __shared__ int sc[BNODES];
    int b = blockIdx.x, t = threadIdx.x;
    unsigned int mask = (1u << bshift) - 1u;
    int nodebase = b << bshift;
    int nodes_here = N - nodebase;
    if (nodes_here > BNODES) nodes_here = BNODES;
    int s = bstart[b], e = bstart[b + 1];
    cnt[t] = 0;
    __syncthreads();
    for (int j = s + t; j < e; j += 1024) atomicAdd(&cnt[es[j] & mask], 1);
    __syncthreads();
    sc[t] = cnt[t];
    __syncthreads();
    for (int off = 1; off < BNODES; off <<= 1) {
        int x = (t >= off) ? sc[t - off] : 0;
        __syncthreads();
        sc[t] += x;
        __syncthreads();
    }
    int excl = sc[t] - cnt[t];
    __syncthreads();
    sc[t] = excl;
    if (t < nodes_here) {
        row_ptr[nodebase + t] = s + excl;
        dinv[nodebase + t] = rsqrtf(1.0f + (float)cnt[t]);
    }
    if (b == nbuck - 1 && t == 0) row_ptr[N] = E;
    __syncthreads();
    for (int j = s + t; j < e; j += 1024) {
        unsigned int p = es[j];
        int local = p & mask;
        int pos = s + atomicAdd(&sc[local], 1);
        col[pos] = (int)(p >> bshift);
    }
}

// ---------------- MFMA matmul ----------------
template <int IN_BF16>
__global__ __launch_bounds__(256) void mm_mfma_kernel(const void* __restrict__ Xv,
                                                      const unsigned int* __restrict__ Wbf,
                                                      const float* __restrict__ dinv,
                                                      unsigned short* __restrict__ Out, int M) {
    __shared__ unsigned int wlds[128 * 64];
    int t = threadIdx.x;
    const uint4* Wv = (const uint4*)Wbf;
#pragma unroll
    for (int it = 0; it < 8; ++it)
        ((uint4*)wlds)[t + it * 256] = Wv[t + it * 256];
    __syncthreads();

    int wv = t >> 6, l = t & 63;
    int l16 = l & 15, lk = l >> 4;
    int rowbase = blockIdx.x * 128 + wv * 32;

    f32x4 acc[2][8];
#pragma unroll
    for (int rt = 0; rt < 2; ++rt)
#pragma unroll
        for (int nt = 0; nt < 8; ++nt) acc[rt][nt] = (f32x4){0.f, 0.f, 0.f, 0.f};

#pragma unroll
    for (int ks = 0; ks < 4; ++ks) {
        U4B afr[2];
#pragma unroll
        for (int rt = 0; rt < 2; ++rt) {
            int row = rowbase + rt * 16 + l16;
            if (IN_BF16) {
                uint4 v = make_uint4(0u, 0u, 0u, 0u);
                if (row < M) v = *((const uint4*)Xv + (size_t)row * 16 + 4 * ks + lk);
                afr[rt].u = v;
            } else {
                const float* X = (const float*)Xv;
                float4 v0 = make_float4(0.f, 0.f, 0.f, 0.f), v1 = v0;
                if (row < M) {
                    v0 = *reinterpret_cast<const float4*>(X + (size_t)row * H + 32 * ks +
                                                          8 * lk);
                    v1 = *reinterpret_cast<const float4*>(X + (size_t)row * H + 32 * ks +
                                                          8 * lk + 4);
                }
                afr[rt].u.x = (unsigned int)f2bf(v0.x) | ((unsigned int)f2bf(v0.y) << 16);
                afr[rt].u.y = (unsigned int)f2bf(v0.z) | ((unsigned int)f2bf(v0.w) << 16);
                afr[rt].u.z = (unsigned int)f2bf(v1.x) | ((unsigned int)f2bf(v1.y) << 16);
                afr[rt].u.w = (unsigned int)f2bf(v1.z) | ((unsigned int)f2bf(v1.w) << 16);
            }
        }
#pragma unroll
        for (int nt = 0; nt < 8; ++nt) {
            int colB = nt * 16 + l16;
            int c = 4 * ks + lk;
            int p = c ^ (colB & 15);
            U4B bfr;
            bfr.u = *reinterpret_cast<const uint4*>(&wlds[colB * 64 + p * 4]);
            acc[0][nt] = __builtin_amdgcn_mfma_f32_16x16x32_bf16(afr[0].b, bfr.b, acc[0][nt],
                                                                 0, 0, 0);
            acc[1][nt] = __builtin_amdgcn_mfma_f32_16x16x32_bf16(afr[1].b, bfr.b, acc[1][nt],
                                                                 0, 0, 0);
        }
    }

#pragma unroll
    for (int rt = 0; rt < 2; ++rt) {
#pragma unroll
        for (int r = 0; r < 4; ++r) {
            int row = rowbase + rt * 16 + lk * 4 + r;
            if (row < M) {
                float dsc = dinv[row];
#pragma unroll
                for (int nt = 0; nt < 8; ++nt)
                    Out[(size_t)row * H + nt * 16 + l16] = f2bf(acc[rt][nt][r] * dsc);
            }
        }
    }
}

// ---------------- aggregation: uint2 gathers, 2 rows per wave ----------------
// Lanes 0-31 own row i_a, lanes 32-63 own row i_b; each lane loads one uint2
// (4 bf16 features). One gather instruction moves 512B (2 rows x 256B).
__global__ __launch_bounds__(256) void agg_bf16_kernel(
    const unsigned int* __restrict__ Au, const int* __restrict__ row_ptr,
    const int* __restrict__ col, const float* __restrict__ dinv,
    const float* __restrict__ bias, unsigned int* __restrict__ OutBf, int N) {
    int wave = threadIdx.x >> 6;
    int lane = threadIdx.x & 63;
    int half = lane >> 5, fl = lane & 31;
    int i = blockIdx.x * 8 + wave * 2 + half;
    if (i >= N) return;
    const uint2* Arow = (const uint2*)Au;  // row stride = 32 uint2
    int s = row_ptr[i], e = row_ptr[i + 1];
    uint2 ws = Arow[(size_t)i * 32 + fl];  // self-loop term
    float a0 = BFLO(ws.x), a1 = BFHI(ws.x), a2 = BFLO(ws.y), a3 = BFHI(ws.y);
    int j = s;
    for (; j + 8 <= e; j += 8) {
        uint2 w[8];
#pragma unroll
        for (int q = 0; q < 8; ++q) w[q] = Arow[(size_t)col[j + q] * 32 + fl];
#pragma unroll
        for (int q = 0; q < 8; ++q) {
            a0 += BFLO(w[q].x);
            a1 += BFHI(w[q].x);
            a2 += BFLO(w[q].y);
            a3 += BFHI(w[q].y);
        }
    }
    for (; j < e; ++j) {
        uint2 w = Arow[(size_t)col[j] * 32 + fl];
        a0 += BFLO(w.x);
        a1 += BFHI(w.x);
        a2 += BFLO(w.y);
        a3 += BFHI(w.y);
    }
    float d = dinv[i];
    float4 bs = *reinterpret_cast<const float4*>(bias + 4 * fl);
    float o0 = fmaxf(fmaf(d, a0, bs.x), 0.f);
    float o1 = fmaxf(fmaf(d, a1, bs.y), 0.f);
    float o2 = fmaxf(fmaf(d, a2, bs.z), 0.f);
    float o3 = fmaxf(fmaf(d, a3, bs.w), 0.f);
    uint2 o;
    o.x = (unsigned int)f2bf(o0) | ((unsigned int)f2bf(o1) << 16);
    o.y = (unsigned int)f2bf(o2) | ((unsigned int)f2bf(o3) << 16);
    ((uint2*)OutBf)[(size_t)i * 32 + fl] = o;
}

// ---------------- pooling (4 waves/block, 4-row unrolled fast path) ------------

__global__ __launch_bounds__(256) void pool_partial(const unsigned int* __restrict__ Bu,
                                                    const int* __restrict__ batch,
                                                    float* __restrict__ gsum, int N) {
    __shared__ int sb[4][PCHUNK];
    int wave = threadIdx.x >> 6, lane = threadIdx.x & 63;
    int base = (blockIdx.x * 4 + wave) * PCHUNK;
    int n_here = N - base;
    if (n_here > PCHUNK) n_here = PCHUNK;
    if (n_here > 0)
        for (int j = lane; j < n_here; j += 64) sb[wave][j] = batch[base + j];
    __syncthreads();
    if (n_here <= 0) return;
    float acc0 = 0.f, acc1 = 0.f;
    int cur = sb[wave][0];
    int j = 0;
    while (j < n_here) {
        if (j + 4 <= n_here && sb[wave][j] == cur && sb[wave][j + 1] == cur &&
            sb[wave][j + 2] == cur && sb[wave][j + 3] == cur) {
            unsigned int w0 = Bu[(size_t)(base + j) * 64 + lane];
            unsigned int w1 = Bu[(size_t)(base + j + 1) * 64 + lane];
            unsigned int w2 = Bu[(size_t)(base + j + 2) * 64 + lane];
            unsigned int w3 = Bu[(size_t)(base + j + 3) * 64 + lane];
            acc0 += BFLO(w0) + BFLO(w1);
            acc1 += BFHI(w0) + BFHI(w1);
            acc0 += BFLO(w2) + BFLO(w3);
            acc1 += BFHI(w2) + BFHI(w3);
            j += 4;
        } else {
            int g = sb[wave][j];
            if (g != cur) {
                atomicAdd(&gsum[cur * H + 2 * lane], acc0);
                atomicAdd(&gsum[cur * H + 2 * lane + 1], acc1);
                acc0 = 0.f;
                acc1 = 0.f;
                cur = g;
            }
            unsigned int w = Bu[(size_t)(base + j) * 64 + lane];
            acc0 += BFLO(w);
            acc1 += BFHI(w);
            ++j;
        }
    }
    atomicAdd(&gsum[cur * H + 2 * lane], acc0);
    atomicAdd(&gsum[cur * H + 2 * lane + 1], acc1);
}

// head + pool_final fused: gv = gsum/cnt
__global__ __launch_bounds__(128) void head_kernel(const float* __restrict__ gsum,
                                                   const int* __restrict__ gstart,
                                                   const float* __restrict__ fW1,
                                                   const float* __restrict__ fb1,
                                                   const float* __restrict__ fW2,
                                                   const float* __restrict__ fb2,
                                                   float* __restrict__ out) {
    __shared__ float gv[H], hid[H], lg[DOUT];
    int gr = blockIdx.x, f = threadIdx.x;
    int cnt = gstart[gr + 1] - gstart[gr];
    gv[f] = gsum[gr * H + f] / fmaxf((float)cnt, 1.f);
    __syncthreads();
    float acc = fb1[f];
    for (int k = 0; k < H; ++k) acc = fmaf(gv[k], fW1[k * H + f], acc);
    hid[f] = fmaxf(acc, 0.f);
    __syncthreads();
    if (f < DOUT) {
        float a = fb2[f];
        for (int k = 0; k < H; ++k) a = fmaf(hid[k], fW2[k * DOUT + f], a);
        lg[f] = a;
    }
    __syncthreads();
    if (f < DOUT) {
        float mx = -1e30f;
        for (int j = 0; j < DOUT; ++j) mx = fmaxf(mx, lg[j]);
        float ssum = 0.f;
        for (int j = 0; j < DOUT; ++j) ssum += expf(lg[j] - mx);
        out[gr * DOUT + f] = expf(lg[f] - mx) / ssum;
    }
}

// ---------------- launch ----------------

extern "C" void kernel_launch(void* const* d_in, const int* in_sizes, int n_in,
                              void* d_out, int out_size, void* d_ws, size_t ws_size,
                              hipStream_t stream) {
    const float* x = (const float*)d_in[0];
    const int* edge = (const int*)d_in[1];
    const int* batch = (const int*)d_in[2];
    const float* W1 = (const float*)d_in[3];
    const float* b1 = (const float*)d_in[4];
    const float* W2 = (const float*)d_in[5];
    const float* b2 = (const float*)d_in[6];
    const float* fW1 = (const float*)d_in[7];
    const float* fb1 = (const float*)d_in[8];
    const float* fW2 = (const float*)d_in[9];
    const float* fb2 = (const float*)d_in[10];
    float* out = (float*)d_out;

    int N = in_sizes[0] / H;
    int E = in_sizes[1] / 2;
    const int* srcI = edge;
    const int* dstI = edge + E;

    char* ws = (char*)d_ws;
    size_t off = 0;
    auto alloc = [&](size_t bytes) {
        void* p = ws + off;
        off = (off + bytes + 255) & ~(size_t)255;
        return p;
    };
    int* row_ptr = (int*)alloc((size_t)(N + 1) * 4);
    int* col = (int*)alloc((size_t)E * 4);
    float* dinv = (float*)alloc((size_t)N * 4);
    int* gstart = (int*)alloc(512);
    int* bctk = (int*)alloc(192 * 4);  // bcnt[128] + tick (zeroed together)
    int* bstart = (int*)alloc((NBUCK_MAX + 1) * 4);
    int* bfill = (int*)alloc(NBUCK_MAX * 4);
    unsigned int* Wbf1 = (unsigned int*)alloc(128 * 64 * 4);
    unsigned int* Wbf2 = (unsigned int*)alloc(128 * 64 * 4);
    float* gsum = (float*)alloc((size_t)NGRAPH * H * 4);
    // A region: holds es (E*4B packed) during CSR build, then bf16 activations
    unsigned short* Abf = (unsigned short*)alloc((size_t)N * H * 4);
    unsigned int* Bbf = (unsigned int*)alloc((size_t)N * H * 4);
    (void)ws_size;

    int* bcnt = bctk;
    int* tick = bctk + 128;
    unsigned int* es = (unsigned int*)Abf;  // consumed by sort2 before mm1 writes

    int bshift = 0;
    while (((N - 1) >> bshift) >= NBUCK_MAX) ++bshift;
    int nbuck = ((N - 1) >> bshift) + 1;

    int nst = (E + SORT_TILE - 1) / SORT_TILE;
    int nbb = (N + 255) / 256;

    hipMemsetAsync(bctk, 0, 192 * 4, stream);
    setup_kernel<<<65 + nbb + nst, 256, 0, stream>>>(batch, N, gstart, W1, W2, Wbf1, Wbf2,
                                                     gsum, dstI, E, bshift, nbuck, nbb, nst,
                                                     bcnt, tick, bstart, bfill);
    bucket_scatter_kernel<<<nst, 256, 0, stream>>>(srcI, dstI, E, bshift, bfill, es);
    bucket_sort2_kernel<<<nbuck, 1024, 0, stream>>>(es, bstart, bshift, nbuck, N, E, col,
                                                    row_ptr, dinv);

    int mmblocks = (N + 127) / 128;
    int aggblocks = (N + 7) / 8;
    mm_mfma_kernel<0><<<mmblocks, 256, 0, stream>>>(x, Wbf1, dinv, Abf, N);
    agg_bf16_kernel<<<aggblocks, 256, 0, stream>>>((const unsigned int*)Abf, row_ptr, col,
                                                   dinv, b1, Bbf, N);
    mm_mfma_kernel<1><<<mmblocks, 256, 0, stream>>>(Bbf, Wbf2, dinv, Abf, N);
    agg_bf16_kernel<<<aggblocks, 256, 0, stream>>>((const unsigned int*)Abf, row_ptr, col,
                                                   dinv, b2, Bbf, N);
    pool_partial<<<(N + 4 * PCHUNK - 1) / (4 * PCHUNK), 256, 0, stream>>>(Bbf, batch, gsum, N);
    head_kernel<<<NGRAPH, 128, 0, stream>>>(gsum, gstart, fW1, fb1, fW2, fb2, out);
}

// Round 14
// 213.393 us; speedup vs baseline: 3.0125x; 1.1887x over previous
//
#include <hip/hip_runtime.h>
#include <hip/hip_bf16.h>

#define H 128
#define DOUT 32
#define NGRAPH 64
#define PCHUNK 64
#define SORT_TILE 4096
#define NBUCK_MAX 128
#define BNODES 1024  // nodes per bucket (bshift=10 for N=100000)

typedef __attribute__((ext_vector_type(8))) short bf16x8;
typedef __attribute__((ext_vector_type(4))) float f32x4;
typedef __attribute__((ext_vector_type(2))) float f32x2;
union U4B {
    uint4 u;
    bf16x8 b;
};

// bf16 helpers (RTN-even pack, bit-shift unpack)
static __device__ __forceinline__ unsigned short f2bf(float v) {
    unsigned int u = __float_as_uint(v);
    unsigned int r = (u + 0x7FFFu + ((u >> 16) & 1u)) >> 16;
    return (unsigned short)r;
}
#define BFLO(w) __uint_as_float((w) << 16)
#define BFHI(w) __uint_as_float((w) & 0xFFFF0000u)

// ---------------- setup: gsum zero + prep_w + batch_bounds + bucket hist -------
__global__ __launch_bounds__(256) void setup_kernel(
    const int* __restrict__ batch, int N, int* __restrict__ gstart,
    const float* __restrict__ W1, const float* __restrict__ W2,
    unsigned int* __restrict__ Wbf1, unsigned int* __restrict__ Wbf2,
    float* __restrict__ gsum, const int* __restrict__ dst, int E, int bshift, int nbuck,
    int nbb, int nst, int* __restrict__ bcnt, int* __restrict__ tick,
    int* __restrict__ bstart, int* __restrict__ bfill) {
    int b = blockIdx.x, t = threadIdx.x;
    if (b == 0) {
        for (int j = t; j < NGRAPH * H; j += 256) gsum[j] = 0.f;
        return;
    }
    if (b <= 64) {
        int pb = b - 1;
        const float* W = (pb < 32) ? W1 : W2;
        unsigned int* Wbf = (pb < 32) ? Wbf1 : Wbf2;
        int q = (pb & 31) * 256 + t;  // 0..8191
        int colq = q >> 6, j = q & 63;
        int p = j >> 2, wI = j & 3;
        int cq = p ^ (colq & 15);
        int k0 = 8 * cq + 2 * wI;
        Wbf[q] = (unsigned int)f2bf(W[k0 * H + colq]) |
                 ((unsigned int)f2bf(W[(k0 + 1) * H + colq]) << 16);
        return;
    }
    if (b <= 64 + nbb) {
        int i = (b - 65) * 256 + t;
        if (i < N) {
            int bb = batch[i];
            int bp = (i == 0) ? -1 : batch[i - 1];
            for (int g = bp + 1; g <= bb; ++g) gstart[g] = i;
            if (i == N - 1)
                for (int g = bb + 1; g <= NGRAPH; ++g) gstart[g] = N;
        }
        return;
    }
    // ---- histogram tile ----
    __shared__ int lh[NBUCK_MAX];
    __shared__ int done;
    __shared__ int scnt[NBUCK_MAX];
    int tile = b - 65 - nbb;
    if (t < NBUCK_MAX) lh[t] = 0;
    __syncthreads();
    int base = tile * SORT_TILE;
    int cnt = E - base;
    if (cnt > SORT_TILE) cnt = SORT_TILE;
    for (int j = t; j < cnt; j += 256) atomicAdd(&lh[dst[base + j] >> bshift], 1);
    __syncthreads();
    if (t < NBUCK_MAX && lh[t]) atomicAdd(&bcnt[t], lh[t]);
    __syncthreads();
    if (t == 0) {
        __threadfence();
        done = (atomicAdd(tick, 1) == nst - 1) ? 1 : 0;
    }
    __syncthreads();
    if (done) {
        if (t < nbuck) scnt[t] = atomicAdd(&bcnt[t], 0);  // coherent read
        __syncthreads();
        if (t == 0) {
            int run = 0;
            for (int k = 0; k < nbuck; ++k) {
                bstart[k] = run;
                bfill[k] = run;
                run += scnt[k];
            }
            bstart[nbuck] = run;  // == E
        }
    }
}

// ---------------- scatter (packed u32 es, direct LDS staging) ----------------
__global__ __launch_bounds__(256) void bucket_scatter_kernel(const int* __restrict__ src,
                                                             const int* __restrict__ dst, int E,
                                                             int bshift, int* __restrict__ bfill,
                                                             unsigned int* __restrict__ es) {
    __shared__ int lh[NBUCK_MAX], lsc[NBUCK_MAX], lbase[NBUCK_MAX], lfill[NBUCK_MAX],
        ldelta[NBUCK_MAX];
    __shared__ unsigned int pk[SORT_TILE];
    __shared__ unsigned char sb[SORT_TILE];
    int t = threadIdx.x;
    unsigned int mask = (1u << bshift) - 1u;
    if (t < NBUCK_MAX) {
        lh[t] = 0;
        lfill[t] = 0;
    }
    __syncthreads();
    int base = blockIdx.x * SORT_TILE;
    int cnt = E - base;
    if (cnt > SORT_TILE) cnt = SORT_TILE;
    for (int j = t; j < cnt; j += 256) atomicAdd(&lh[dst[base + j] >> bshift], 1);
    __syncthreads();
    if (t < NBUCK_MAX) lsc[t] = lh[t];
    __syncthreads();
    for (int off = 1; off < NBUCK_MAX; off <<= 1) {
        int x = 0;
        if (t < NBUCK_MAX && t >= off) x = lsc[t - off];
        __syncthreads();
        if (t < NBUCK_MAX) lsc[t] += x;
        __syncthreads();
    }
    if (t < NBUCK_MAX) {
        lbase[t] = lsc[t] - lh[t];
        if (lh[t] > 0) ldelta[t] = atomicAdd(&bfill[t], lh[t]) - lbase[t];
    }
    __syncthreads();
    for (int j = t; j < cnt; j += 256) {
        int d = dst[base + j];
        int b = d >> bshift;
        int r = atomicAdd(&lfill[b], 1);
        int slot = lbase[b] + r;
        pk[slot] = ((unsigned int)src[base + j] << bshift) | ((unsigned int)d & mask);
        sb[slot] = (unsigned char)b;
    }
    __syncthreads();
    for (int s = t; s < cnt; s += 256) {
        es[ldelta[sb[s]] + s] = pk[s];
    }
}

// ---------------- per-bucket counting sort: emits col, row_ptr, dinv ----------
__global__ __launch_bounds__(1024) void bucket_sort2_kernel(const unsigned int* __restrict__ es,
                                                            const int* __restrict__ bstart,
                                                            int bshift, int nbuck, int N, int E,
                                                            int* __restrict__ col,
                                                            int* __restrict__ row_ptr,
                                                            float* __restrict__ dinv) {
    __shared__ int cnt[BNODES];
    __shared__ int sc[BNODES];
    int b = blockIdx.x, t = threadIdx.x;
    unsigned int mask = (1u << bshift) - 1u;
    int nodebase = b << bshift;
    int nodes_here = N - nodebase;
    if (nodes_here > BNODES) nodes_here = BNODES;
    int s = bstart[b], e = bstart[b + 1];
    cnt[t] = 0;
    __syncthreads();
    for (int j = s + t; j < e; j += 1024) atomicAdd(&cnt[es[j] & mask], 1);
    __syncthreads();
    sc[t] = cnt[t];
    __syncthreads();
    for (int off = 1; off < BNODES; off <<= 1) {
        int x = (t >= off) ? sc[t - off] : 0;
        __syncthreads();
        sc[t] += x;
        __syncthreads();
    }
    int excl = sc[t] - cnt[t];
    __syncthreads();
    sc[t] = excl;
    if (t < nodes_here) {
        row_ptr[nodebase + t] = s + excl;
        dinv[nodebase + t] = rsqrtf(1.0f + (float)cnt[t]);
    }
    if (b == nbuck - 1 && t == 0) row_ptr[N] = E;
    __syncthreads();
    for (int j = s + t; j < e; j += 1024) {
        unsigned int p = es[j];
        int local = p & mask;
        int pos = s + atomicAdd(&sc[local], 1);
        col[pos] = (int)(p >> bshift);
    }
}

// ---------------- MFMA matmul (fp8 e4m3 output: the gathered operand) ---------
template <int IN_BF16>
__global__ __launch_bounds__(256) void mm_mfma_kernel(const void* __restrict__ Xv,
                                                      const unsigned int* __restrict__ Wbf,
                                                      const float* __restrict__ dinv,
                                                      unsigned char* __restrict__ Out, int M) {
    __shared__ unsigned int wlds[128 * 64];
    int t = threadIdx.x;
    const uint4* Wv = (const uint4*)Wbf;
#pragma unroll
    for (int it = 0; it < 8; ++it)
        ((uint4*)wlds)[t + it * 256] = Wv[t + it * 256];
    __syncthreads();

    int wv = t >> 6, l = t & 63;
    int l16 = l & 15, lk = l >> 4;
    int rowbase = blockIdx.x * 128 + wv * 32;

    f32x4 acc[2][8];
#pragma unroll
    for (int rt = 0; rt < 2; ++rt)
#pragma unroll
        for (int nt = 0; nt < 8; ++nt) acc[rt][nt] = (f32x4){0.f, 0.f, 0.f, 0.f};

#pragma unroll
    for (int ks = 0; ks < 4; ++ks) {
        U4B afr[2];
#pragma unroll
        for (int rt = 0; rt < 2; ++rt) {
            int row = rowbase + rt * 16 + l16;
            if (IN_BF16) {
                uint4 v = make_uint4(0u, 0u, 0u, 0u);
                if (row < M) v = *((const uint4*)Xv + (size_t)row * 16 + 4 * ks + lk);
                afr[rt].u = v;
            } else {
                const float* X = (const float*)Xv;
                float4 v0 = make_float4(0.f, 0.f, 0.f, 0.f), v1 = v0;
                if (row < M) {
                    v0 = *reinterpret_cast<const float4*>(X + (size_t)row * H + 32 * ks +
                                                          8 * lk);
                    v1 = *reinterpret_cast<const float4*>(X + (size_t)row * H + 32 * ks +
                                                          8 * lk + 4);
                }
                afr[rt].u.x = (unsigned int)f2bf(v0.x) | ((unsigned int)f2bf(v0.y) << 16);
                afr[rt].u.y = (unsigned int)f2bf(v0.z) | ((unsigned int)f2bf(v0.w) << 16);
                afr[rt].u.z = (unsigned int)f2bf(v1.x) | ((unsigned int)f2bf(v1.y) << 16);
                afr[rt].u.w = (unsigned int)f2bf(v1.z) | ((unsigned int)f2bf(v1.w) << 16);
            }
        }
#pragma unroll
        for (int nt = 0; nt < 8; ++nt) {
            int colB = nt * 16 + l16;
            int c = 4 * ks + lk;
            int p = c ^ (colB & 15);
            U4B bfr;
            bfr.u = *reinterpret_cast<const uint4*>(&wlds[colB * 64 + p * 4]);
            acc[0][nt] = __builtin_amdgcn_mfma_f32_16x16x32_bf16(afr[0].b, bfr.b, acc[0][nt],
                                                                 0, 0, 0);
            acc[1][nt] = __builtin_amdgcn_mfma_f32_16x16x32_bf16(afr[1].b, bfr.b, acc[1][nt],
                                                                 0, 0, 0);
        }
    }

#pragma unroll
    for (int rt = 0; rt < 2; ++rt) {
#pragma unroll
        for (int r = 0; r < 4; ++r) {
            int row = rowbase + rt * 16 + lk * 4 + r;
            if (row < M) {
                float dsc = dinv[row];
                unsigned char* Orow = Out + (size_t)row * H;
#pragma unroll
                for (int nt = 0; nt < 8; ++nt) {
                    int pk8 = __builtin_amdgcn_cvt_pk_fp8_f32(acc[rt][nt][r] * dsc, 0.f, 0, 0);
                    Orow[nt * 16 + l16] = (unsigned char)(pk8 & 0xFF);
                }
            }
        }
    }
}

// ---------------- aggregation: fp8 gathers (128B/row = 1 line), 2 rows/wave ----
// Lanes 0-31 own row i_a, lanes 32-63 own row i_b; lane fl loads one u32
// (4 fp8 features 4*fl..4*fl+3). Accumulate fp32, write bf16 (uint2).
__global__ __launch_bounds__(256) void agg_fp8_kernel(
    const unsigned int* __restrict__ Au, const int* __restrict__ row_ptr,
    const int* __restrict__ col, const float* __restrict__ dinv,
    const float* __restrict__ bias, unsigned int* __restrict__ OutBf, int N) {
    int wave = threadIdx.x >> 6;
    int lane = threadIdx.x & 63;
    int half = lane >> 5, fl = lane & 31;
    int i = blockIdx.x * 8 + wave * 2 + half;
    if (i >= N) return;
    int s = row_ptr[i], e = row_ptr[i + 1];
    unsigned int ws = Au[(size_t)i * 32 + fl];  // self-loop term (4 fp8)
    f32x2 slo = __builtin_amdgcn_cvt_pk_f32_fp8((int)ws, false);
    f32x2 shi = __builtin_amdgcn_cvt_pk_f32_fp8((int)ws, true);
    float a0 = slo[0], a1 = slo[1], a2 = shi[0], a3 = shi[1];
    int j = s;
    for (; j + 8 <= e; j += 8) {
        unsigned int w[8];
#pragma unroll
        for (int q = 0; q < 8; ++q) w[q] = Au[(size_t)col[j + q] * 32 + fl];
#pragma unroll
        for (int q = 0; q < 8; ++q) {
            f32x2 lo = __builtin_amdgcn_cvt_pk_f32_fp8((int)w[q], false);
            f32x2 hi = __builtin_amdgcn_cvt_pk_f32_fp8((int)w[q], true);
            a0 += lo[0];
            a1 += lo[1];
            a2 += hi[0];
            a3 += hi[1];
        }
    }
    for (; j < e; ++j) {
        unsigned int w = Au[(size_t)col[j] * 32 + fl];
        f32x2 lo = __builtin_amdgcn_cvt_pk_f32_fp8((int)w, false);
        f32x2 hi = __builtin_amdgcn_cvt_pk_f32_fp8((int)w, true);
        a0 += lo[0];
        a1 += lo[1];
        a2 += hi[0];
        a3 += hi[1];
    }
    float d = dinv[i];
    float4 bs = *reinterpret_cast<const float4*>(bias + 4 * fl);
    float o0 = fmaxf(fmaf(d, a0, bs.x), 0.f);
    float o1 = fmaxf(fmaf(d, a1, bs.y), 0.f);
    float o2 = fmaxf(fmaf(d, a2, bs.z), 0.f);
    float o3 = fmaxf(fmaf(d, a3, bs.w), 0.f);
    uint2 o;
    o.x = (unsigned int)f2bf(o0) | ((unsigned int)f2bf(o1) << 16);
    o.y = (unsigned int)f2bf(o2) | ((unsigned int)f2bf(o3) << 16);
    ((uint2*)OutBf)[(size_t)i * 32 + fl] = o;
}

// ---------------- pooling (4 waves/block, 4-row unrolled fast path) ------------

__global__ __launch_bounds__(256) void pool_partial(const unsigned int* __restrict__ Bu,
                                                    const int* __restrict__ batch,
                                                    float* __restrict__ gsum, int N) {
    __shared__ int sb[4][PCHUNK];
    int wave = threadIdx.x >> 6, lane = threadIdx.x & 63;
    int base = (blockIdx.x * 4 + wave) * PCHUNK;
    int n_here = N - base;
    if (n_here > PCHUNK) n_here = PCHUNK;
    if (n_here > 0)
        for (int j = lane; j < n_here; j += 64) sb[wave][j] = batch[base + j];
    __syncthreads();
    if (n_here <= 0) return;
    float acc0 = 0.f, acc1 = 0.f;
    int cur = sb[wave][0];
    int j = 0;
    while (j < n_here) {
        if (j + 4 <= n_here && sb[wave][j] == cur && sb[wave][j + 1] == cur &&
            sb[wave][j + 2] == cur && sb[wave][j + 3] == cur) {
            unsigned int w0 = Bu[(size_t)(base + j) * 64 + lane];
            unsigned int w1 = Bu[(size_t)(base + j + 1) * 64 + lane];
            unsigned int w2 = Bu[(size_t)(base + j + 2) * 64 + lane];
            unsigned int w3 = Bu[(size_t)(base + j + 3) * 64 + lane];
            acc0 += BFLO(w0) + BFLO(w1);
            acc1 += BFHI(w0) + BFHI(w1);
            acc0 += BFLO(w2) + BFLO(w3);
            acc1 += BFHI(w2) + BFHI(w3);
            j += 4;
        } else {
            int g = sb[wave][j];
            if (g != cur) {
                atomicAdd(&gsum[cur * H + 2 * lane], acc0);
                atomicAdd(&gsum[cur * H + 2 * lane + 1], acc1);
                acc0 = 0.f;
                acc1 = 0.f;
                cur = g;
            }
            unsigned int w = Bu[(size_t)(base + j) * 64 + lane];
            acc0 += BFLO(w);
            acc1 += BFHI(w);
            ++j;
        }
    }
    atomicAdd(&gsum[cur * H + 2 * lane], acc0);
    atomicAdd(&gsum[cur * H + 2 * lane + 1], acc1);
}

// head + pool_final fused: gv = gsum/cnt
__global__ __launch_bounds__(128) void head_kernel(const float* __restrict__ gsum,
                                                   const int* __restrict__ gstart,
                                                   const float* __restrict__ fW1,
                                                   const float* __restrict__ fb1,
                                                   const float* __restrict__ fW2,
                                                   const float* __restrict__ fb2,
                                                   float* __restrict__ out) {
    __shared__ float gv[H], hid[H], lg[DOUT];
    int gr = blockIdx.x, f = threadIdx.x;
    int cnt = gstart[gr + 1] - gstart[gr];
    gv[f] = gsum[gr * H + f] / fmaxf((float)cnt, 1.f);
    __syncthreads();
    float acc = fb1[f];
    for (int k = 0; k < H; ++k) acc = fmaf(gv[k], fW1[k * H + f], acc);
    hid[f] = fmaxf(acc, 0.f);
    __syncthreads();
    if (f < DOUT) {
        float a = fb2[f];
        for (int k = 0; k < H; ++k) a = fmaf(hid[k], fW2[k * DOUT + f], a);
        lg[f] = a;
    }
    __syncthreads();
    if (f < DOUT) {
        float mx = -1e30f;
        for (int j = 0; j < DOUT; ++j) mx = fmaxf(mx, lg[j]);
        float ssum = 0.f;
        for (int j = 0; j < DOUT; ++j) ssum += expf(lg[j] - mx);
        out[gr * DOUT + f] = expf(lg[f] - mx) / ssum;
    }
}

// ---------------- launch ----------------

extern "C" void kernel_launch(void* const* d_in, const int* in_sizes, int n_in,
                              void* d_out, int out_size, void* d_ws, size_t ws_size,
                              hipStream_t stream) {
    const float* x = (const float*)d_in[0];
    const int* edge = (const int*)d_in[1];
    const int* batch = (const int*)d_in[2];
    const float* W1 = (const float*)d_in[3];
    const float* b1 = (const float*)d_in[4];
    const float* W2 = (const float*)d_in[5];
    const float* b2 = (const float*)d_in[6];
    const float* fW1 = (const float*)d_in[7];
    const float* fb1 = (const float*)d_in[8];
    const float* fW2 = (const float*)d_in[9];
    const float* fb2 = (const float*)d_in[10];
    float* out = (float*)d_out;

    int N = in_sizes[0] / H;
    int E = in_sizes[1] / 2;
    const int* srcI = edge;
    const int* dstI = edge + E;

    char* ws = (char*)d_ws;
    size_t off = 0;
    auto alloc = [&](size_t bytes) {
        void* p = ws + off;
        off = (off + bytes + 255) & ~(size_t)255;
        return p;
    };
    int* row_ptr = (int*)alloc((size_t)(N + 1) * 4);
    int* col = (int*)alloc((size_t)E * 4);
    float* dinv = (float*)alloc((size_t)N * 4);
    int* gstart = (int*)alloc(512);
    int* bctk = (int*)alloc(192 * 4);  // bcnt[128] + tick (zeroed together)
    int* bstart = (int*)alloc((NBUCK_MAX + 1) * 4);
    int* bfill = (int*)alloc(NBUCK_MAX * 4);
    unsigned int* Wbf1 = (unsigned int*)alloc(128 * 64 * 4);
    unsigned int* Wbf2 = (unsigned int*)alloc(128 * 64 * 4);
    float* gsum = (float*)alloc((size_t)NGRAPH * H * 4);
    // A region: holds es (E*4B packed) during CSR build, then fp8 activations
    unsigned char* Af8 = (unsigned char*)alloc((size_t)N * H * 4);
    unsigned int* Bbf = (unsigned int*)alloc((size_t)N * H * 4);
    (void)ws_size;

    int* bcnt = bctk;
    int* tick = bctk + 128;
    unsigned int* es = (unsigned int*)Af8;  // consumed by sort2 before mm1 writes

    int bshift = 0;
    while (((N - 1) >> bshift) >= NBUCK_MAX) ++bshift;
    int nbuck = ((N - 1) >> bshift) + 1;

    int nst = (E + SORT_TILE - 1) / SORT_TILE;
    int nbb = (N + 255) / 256;

    hipMemsetAsync(bctk, 0, 192 * 4, stream);
    setup_kernel<<<65 + nbb + nst, 256, 0, stream>>>(batch, N, gstart, W1, W2, Wbf1, Wbf2,
                                                     gsum, dstI, E, bshift, nbuck, nbb, nst,
                                                     bcnt, tick, bstart, bfill);
    bucket_scatter_kernel<<<nst, 256, 0, stream>>>(srcI, dstI, E, bshift, bfill, es);
    bucket_sort2_kernel<<<nbuck, 1024, 0, stream>>>(es, bstart, bshift, nbuck, N, E, col,
                                                    row_ptr, dinv);

    int mmblocks = (N + 127) / 128;
    int aggblocks = (N + 7) / 8;
    mm_mfma_kernel<0><<<mmblocks, 256, 0, stream>>>(x, Wbf1, dinv, Af8, N);
    agg_fp8_kernel<<<aggblocks, 256, 0, stream>>>((const unsigned int*)Af8, row_ptr, col,
                                                  dinv, b1, Bbf, N);
    mm_mfma_kernel<1><<<mmblocks, 256, 0, stream>>>(Bbf, Wbf2, dinv, Af8, N);
    agg_fp8_kernel<<<aggblocks, 256, 0, stream>>>((const unsigned int*)Af8, row_ptr, col,
                                                  dinv, b2, Bbf, N);
    pool_partial<<<(N + 4 * PCHUNK - 1) / (4 * PCHUNK), 256, 0, stream>>>(Bbf, batch, gsum, N);
    head_kernel<<<NGRAPH, 128, 0, stream>>>(gsum, gstart, fW1, fb1, fW2, fb2, out);
}

// Round 15
// 205.334 us; speedup vs baseline: 3.1307x; 1.0393x over previous
//
#include <hip/hip_runtime.h>
#include <hip/hip_bf16.h>

#define H 128
#define DOUT 32
#define NGRAPH 64
#define PCHUNK 64
#define SORT_TILE 4096
#define NBUCK_MAX 128
#define BNODES 1024  // nodes per bucket (bshift=10 for N=100000)

typedef __attribute__((ext_vector_type(8))) short bf16x8;
typedef __attribute__((ext_vector_type(4))) float f32x4;
typedef __attribute__((ext_vector_type(2))) float f32x2;
union U4B {
    uint4 u;
    bf16x8 b;
};

// bf16 helpers (RTN-even pack, bit-shift unpack)
static __device__ __forceinline__ unsigned short f2bf(float v) {
    unsigned int u = __float_as_uint(v);
    unsigned int r = (u + 0x7FFFu + ((u >> 16) & 1u)) >> 16;
    return (unsigned short)r;
}
#define BFLO(w) __uint_as_float((w) << 16)
#define BFHI(w) __uint_as_float((w) & 0xFFFF0000u)

// ---------------- setup: gsum zero + prep_w + batch_bounds + bucket hist -------
__global__ __launch_bounds__(256) void setup_kernel(
    const int* __restrict__ batch, int N, int* __restrict__ gstart,
    const float* __restrict__ W1, const float* __restrict__ W2,
    unsigned int* __restrict__ Wbf1, unsigned int* __restrict__ Wbf2,
    float* __restrict__ gsum, const int* __restrict__ dst, int E, int bshift, int nbuck,
    int nbb, int nst, int* __restrict__ bcnt, int* __restrict__ tick,
    int* __restrict__ bstart, int* __restrict__ bfill) {
    int b = blockIdx.x, t = threadIdx.x;
    if (b == 0) {
        for (int j = t; j < NGRAPH * H; j += 256) gsum[j] = 0.f;
        return;
    }
    if (b <= 64) {
        int pb = b - 1;
        const float* W = (pb < 32) ? W1 : W2;
        unsigned int* Wbf = (pb < 32) ? Wbf1 : Wbf2;
        int q = (pb & 31) * 256 + t;  // 0..8191
        int colq = q >> 6, j = q & 63;
        int p = j >> 2, wI = j & 3;
        int cq = p ^ (colq & 15);
        int k0 = 8 * cq + 2 * wI;
        Wbf[q] = (unsigned int)f2bf(W[k0 * H + colq]) |
                 ((unsigned int)f2bf(W[(k0 + 1) * H + colq]) << 16);
        return;
    }
    if (b <= 64 + nbb) {
        int i = (b - 65) * 256 + t;
        if (i < N) {
            int bb = batch[i];
            int bp = (i == 0) ? -1 : batch[i - 1];
            for (int g = bp + 1; g <= bb; ++g) gstart[g] = i;
            if (i == N - 1)
                for (int g = bb + 1; g <= NGRAPH; ++g) gstart[g] = N;
        }
        return;
    }
    // ---- histogram tile ----
    __shared__ int lh[NBUCK_MAX];
    __shared__ int done;
    __shared__ int scnt[NBUCK_MAX];
    int tile = b - 65 - nbb;
    if (t < NBUCK_MAX) lh[t] = 0;
    __syncthreads();
    int base = tile * SORT_TILE;
    int cnt = E - base;
    if (cnt > SORT_TILE) cnt = SORT_TILE;
    for (int j = t; j < cnt; j += 256) atomicAdd(&lh[dst[base + j] >> bshift], 1);
    __syncthreads();
    if (t < NBUCK_MAX && lh[t]) atomicAdd(&bcnt[t], lh[t]);
    __syncthreads();
    if (t == 0) {
        __threadfence();
        done = (atomicAdd(tick, 1) == nst - 1) ? 1 : 0;
    }
    __syncthreads();
    if (done) {
        if (t < nbuck) scnt[t] = atomicAdd(&bcnt[t], 0);  // coherent read
        __syncthreads();
        if (t == 0) {
            int run = 0;
            for (int k = 0; k < nbuck; ++k) {
                bstart[k] = run;
                bfill[k] = run;
                run += scnt[k];
            }
            bstart[nbuck] = run;  // == E
        }
    }
}

// ---------------- scatter: direct write, 1.5KB LDS, full occupancy ------------
// es entry = (src << bshift) | (dst & mask). Within-bucket order is arbitrary
// (sort2 re-sorts per node).
__global__ __launch_bounds__(256) void bucket_scatter_kernel(const int* __restrict__ src,
                                                             const int* __restrict__ dst, int E,
                                                             int bshift, int* __restrict__ bfill,
                                                             unsigned int* __restrict__ es) {
    __shared__ int lh[NBUCK_MAX], lfill[NBUCK_MAX], gbase[NBUCK_MAX];
    int t = threadIdx.x;
    unsigned int mask = (1u << bshift) - 1u;
    if (t < NBUCK_MAX) {
        lh[t] = 0;
        lfill[t] = 0;
    }
    __syncthreads();
    int base = blockIdx.x * SORT_TILE;
    int cnt = E - base;
    if (cnt > SORT_TILE) cnt = SORT_TILE;
    for (int j = t; j < cnt; j += 256) atomicAdd(&lh[dst[base + j] >> bshift], 1);
    __syncthreads();
    if (t < NBUCK_MAX && lh[t] > 0) gbase[t] = atomicAdd(&bfill[t], lh[t]);
    __syncthreads();
    for (int j = t; j < cnt; j += 256) {
        int d = dst[base + j];
        int b = d >> bshift;
        int r = atomicAdd(&lfill[b], 1);
        es[gbase[b] + r] = ((unsigned int)src[base + j] << bshift) | ((unsigned int)d & mask);
    }
}

// ---------------- per-bucket counting sort: emits col, row_ptr, dinv ----------
__global__ __launch_bounds__(1024) void bucket_sort2_kernel(const unsigned int* __restrict__ es,
                                                            const int* __restrict__ bstart,
                                                            int bshift, int nbuck, int N, int E,
                                                            int* __restrict__ col,
                                                            int* __restrict__ row_ptr,
                                                            float* __restrict__ dinv) {
    __shared__ int cnt[BNODES];
    __shared__ int sc[BNODES];
    int b = blockIdx.x, t = threadIdx.x;
    unsigned int mask = (1u << bshift) - 1u;
    int nodebase = b << bshift;
    int nodes_here = N - nodebase;
    if (nodes_here > BNODES) nodes_here = BNODES;
    int s = bstart[b], e = bstart[b + 1];
    cnt[t] = 0;
    __syncthreads();
    for (int j = s + t; j < e; j += 1024) atomicAdd(&cnt[es[j] & mask], 1);
    __syncthreads();
    sc[t] = cnt[t];
    __syncthreads();
    for (int off = 1; off < BNODES; off <<= 1) {
        int x = (t >= off) ? sc[t - off] : 0;
        __syncthreads();
        sc[t] += x;
        __syncthreads();
    }
    int excl = sc[t] - cnt[t];
    __syncthreads();
    sc[t] = excl;
    if (t < nodes_here) {
        row_ptr[nodebase + t] = s + excl;
        dinv[nodebase + t] = rsqrtf(1.0f + (float)cnt[t]);
    }
    if (b == nbuck - 1 && t == 0) row_ptr[N] = E;
    __syncthreads();
    for (int j = s + t; j < e; j += 1024) {
        unsigned int p = es[j];
        int local = p & mask;
        int pos = s + atomicAdd(&sc[local], 1);
        col[pos] = (int)(p >> bshift);
    }
}

// ---------------- MFMA matmul (fp8 e4m3 output: the gathered operand) ---------
template <int IN_BF16>
__global__ __launch_bounds__(256) void mm_mfma_kernel(const void* __restrict__ Xv,
                                                      const unsigned int* __restrict__ Wbf,
                                                      const float* __restrict__ dinv,
                                                      unsigned char* __restrict__ Out, int M) {
    __shared__ unsigned int wlds[128 * 64];
    int t = threadIdx.x;
    const uint4* Wv = (const uint4*)Wbf;
#pragma unroll
    for (int it = 0; it < 8; ++it)
        ((uint4*)wlds)[t + it * 256] = Wv[t + it * 256];
    __syncthreads();

    int wv = t >> 6, l = t & 63;
    int l16 = l & 15, lk = l >> 4;
    int rowbase = blockIdx.x * 128 + wv * 32;

    f32x4 acc[2][8];
#pragma unroll
    for (int rt = 0; rt < 2; ++rt)
#pragma unroll
        for (int nt = 0; nt < 8; ++nt) acc[rt][nt] = (f32x4){0.f, 0.f, 0.f, 0.f};

#pragma unroll
    for (int ks = 0; ks < 4; ++ks) {
        U4B afr[2];
#pragma unroll
        for (int rt = 0; rt < 2; ++rt) {
            int row = rowbase + rt * 16 + l16;
            if (IN_BF16) {
                uint4 v = make_uint4(0u, 0u, 0u, 0u);
                if (row < M) v = *((const uint4*)Xv + (size_t)row * 16 + 4 * ks + lk);
                afr[rt].u = v;
            } else {
                const float* X = (const float*)Xv;
                float4 v0 = make_float4(0.f, 0.f, 0.f, 0.f), v1 = v0;
                if (row < M) {
                    v0 = *reinterpret_cast<const float4*>(X + (size_t)row * H + 32 * ks +
                                                          8 * lk);
                    v1 = *reinterpret_cast<const float4*>(X + (size_t)row * H + 32 * ks +
                                                          8 * lk + 4);
                }
                afr[rt].u.x = (unsigned int)f2bf(v0.x) | ((unsigned int)f2bf(v0.y) << 16);
                afr[rt].u.y = (unsigned int)f2bf(v0.z) | ((unsigned int)f2bf(v0.w) << 16);
                afr[rt].u.z = (unsigned int)f2bf(v1.x) | ((unsigned int)f2bf(v1.y) << 16);
                afr[rt].u.w = (unsigned int)f2bf(v1.z) | ((unsigned int)f2bf(v1.w) << 16);
            }
        }
#pragma unroll
        for (int nt = 0; nt < 8; ++nt) {
            int colB = nt * 16 + l16;
            int c = 4 * ks + lk;
            int p = c ^ (colB & 15);
            U4B bfr;
            bfr.u = *reinterpret_cast<const uint4*>(&wlds[colB * 64 + p * 4]);
            acc[0][nt] = __builtin_amdgcn_mfma_f32_16x16x32_bf16(afr[0].b, bfr.b, acc[0][nt],
                                                                 0, 0, 0);
            acc[1][nt] = __builtin_amdgcn_mfma_f32_16x16x32_bf16(afr[1].b, bfr.b, acc[1][nt],
                                                                 0, 0, 0);
        }
    }

#pragma unroll
    for (int rt = 0; rt < 2; ++rt) {
#pragma unroll
        for (int r = 0; r < 4; ++r) {
            int row = rowbase + rt * 16 + lk * 4 + r;
            if (row < M) {
                float dsc = dinv[row];
                unsigned char* Orow = Out + (size_t)row * H;
#pragma unroll
                for (int nt = 0; nt < 8; ++nt) {
                    int pk8 = __builtin_amdgcn_cvt_pk_fp8_f32(acc[rt][nt][r] * dsc, 0.f, 0, 0);
                    Orow[nt * 16 + l16] = (unsigned char)(pk8 & 0xFF);
                }
            }
        }
    }
}

// ---------------- aggregation: fp8 gathers, 16-deep, 2 rows/wave --------------
__global__ __launch_bounds__(256) void agg_fp8_kernel(
    const unsigned int* __restrict__ Au, const int* __restrict__ row_ptr,
    const int* __restrict__ col, const float* __restrict__ dinv,
    const float* __restrict__ bias, unsigned int* __restrict__ OutBf, int N) {
    int wave = threadIdx.x >> 6;
    int lane = threadIdx.x & 63;
    int half = lane >> 5, fl = lane & 31;
    int i = blockIdx.x * 8 + wave * 2 + half;
    if (i >= N) return;
    int s = row_ptr[i], e = row_ptr[i + 1];
    unsigned int ws = Au[(size_t)i * 32 + fl];  // self-loop term (4 fp8)
    f32x2 slo = __builtin_amdgcn_cvt_pk_f32_fp8((int)ws, false);
    f32x2 shi = __builtin_amdgcn_cvt_pk_f32_fp8((int)ws, true);
    float a0 = slo[0], a1 = slo[1], a2 = shi[0], a3 = shi[1];
    int j = s;
    for (; j + 16 <= e; j += 16) {
        unsigned int w[16];
#pragma unroll
        for (int q = 0; q < 16; ++q) w[q] = Au[(size_t)col[j + q] * 32 + fl];
#pragma unroll
        for (int q = 0; q < 16; ++q) {
            f32x2 lo = __builtin_amdgcn_cvt_pk_f32_fp8((int)w[q], false);
            f32x2 hi = __builtin_amdgcn_cvt_pk_f32_fp8((int)w[q], true);
            a0 += lo[0];
            a1 += lo[1];
            a2 += hi[0];
            a3 += hi[1];
        }
    }
    for (; j + 4 <= e; j += 4) {
        unsigned int w[4];
#pragma unroll
        for (int q = 0; q < 4; ++q) w[q] = Au[(size_t)col[j + q] * 32 + fl];
#pragma unroll
        for (int q = 0; q < 4; ++q) {
            f32x2 lo = __builtin_amdgcn_cvt_pk_f32_fp8((int)w[q], false);
            f32x2 hi = __builtin_amdgcn_cvt_pk_f32_fp8((int)w[q], true);
            a0 += lo[0];
            a1 += lo[1];
            a2 += hi[0];
            a3 += hi[1];
        }
    }
    for (; j < e; ++j) {
        unsigned int w = Au[(size_t)col[j] * 32 + fl];
        f32x2 lo = __builtin_amdgcn_cvt_pk_f32_fp8((int)w, false);
        f32x2 hi = __builtin_amdgcn_cvt_pk_f32_fp8((int)w, true);
        a0 += lo[0];
        a1 += lo[1];
        a2 += hi[0];
        a3 += hi[1];
    }
    float d = dinv[i];
    float4 bs = *reinterpret_cast<const float4*>(bias + 4 * fl);
    float o0 = fmaxf(fmaf(d, a0, bs.x), 0.f);
    float o1 = fmaxf(fmaf(d, a1, bs.y), 0.f);
    float o2 = fmaxf(fmaf(d, a2, bs.z), 0.f);
    float o3 = fmaxf(fmaf(d, a3, bs.w), 0.f);
    uint2 o;
    o.x = (unsigned int)f2bf(o0) | ((unsigned int)f2bf(o1) << 16);
    o.y = (unsigned int)f2bf(o2) | ((unsigned int)f2bf(o3) << 16);
    ((uint2*)OutBf)[(size_t)i * 32 + fl] = o;
}

// ---------------- pooling (4 waves/block, 4-row unrolled fast path) ------------

__global__ __launch_bounds__(256) void pool_partial(const unsigned int* __restrict__ Bu,
                                                    const int* __restrict__ batch,
                                                    float* __restrict__ gsum, int N) {
    __shared__ int sb[4][PCHUNK];
    int wave = threadIdx.x >> 6, lane = threadIdx.x & 63;
    int base = (blockIdx.x * 4 + wave) * PCHUNK;
    int n_here = N - base;
    if (n_here > PCHUNK) n_here = PCHUNK;
    if (n_here > 0)
        for (int j = lane; j < n_here; j += 64) sb[wave][j] = batch[base + j];
    __syncthreads();
    if (n_here <= 0) return;
    float acc0 = 0.f, acc1 = 0.f;
    int cur = sb[wave][0];
    int j = 0;
    while (j < n_here) {
        if (j + 4 <= n_here && sb[wave][j] == cur && sb[wave][j + 1] == cur &&
            sb[wave][j + 2] == cur && sb[wave][j + 3] == cur) {
            unsigned int w0 = Bu[(size_t)(base + j) * 64 + lane];
            unsigned int w1 = Bu[(size_t)(base + j + 1) * 64 + lane];
            unsigned int w2 = Bu[(size_t)(base + j + 2) * 64 + lane];
            unsigned int w3 = Bu[(size_t)(base + j + 3) * 64 + lane];
            acc0 += BFLO(w0) + BFLO(w1);
            acc1 += BFHI(w0) + BFHI(w1);
            acc0 += BFLO(w2) + BFLO(w3);
            acc1 += BFHI(w2) + BFHI(w3);
            j += 4;
        } else {
            int g = sb[wave][j];
            if (g != cur) {
                atomicAdd(&gsum[cur * H + 2 * lane], acc0);
                atomicAdd(&gsum[cur * H + 2 * lane + 1], acc1);
                acc0 = 0.f;
                acc1 = 0.f;
                cur = g;
            }
            unsigned int w = Bu[(size_t)(base + j) * 64 + lane];
            acc0 += BFLO(w);
            acc1 += BFHI(w);
            ++j;
        }
    }
    atomicAdd(&gsum[cur * H + 2 * lane], acc0);
    atomicAdd(&gsum[cur * H + 2 * lane + 1], acc1);
}

// head + pool_final fused: gv = gsum/cnt
__global__ __launch_bounds__(128) void head_kernel(const float* __restrict__ gsum,
                                                   const int* __restrict__ gstart,
                                                   const float* __restrict__ fW1,
                                                   const float* __restrict__ fb1,
                                                   const float* __restrict__ fW2,
                                                   const float* __restrict__ fb2,
                                                   float* __restrict__ out) {
    __shared__ float gv[H], hid[H], lg[DOUT];
    int gr = blockIdx.x, f = threadIdx.x;
    int cnt = gstart[gr + 1] - gstart[gr];
    gv[f] = gsum[gr * H + f] / fmaxf((float)cnt, 1.f);
    __syncthreads();
    float acc = fb1[f];
    for (int k = 0; k < H; ++k) acc = fmaf(gv[k], fW1[k * H + f], acc);
    hid[f] = fmaxf(acc, 0.f);
    __syncthreads();
    if (f < DOUT) {
        float a = fb2[f];
        for (int k = 0; k < H; ++k) a = fmaf(hid[k], fW2[k * DOUT + f], a);
        lg[f] = a;
    }
    __syncthreads();
    if (f < DOUT) {
        float mx = -1e30f;
        for (int j = 0; j < DOUT; ++j) mx = fmaxf(mx, lg[j]);
        float ssum = 0.f;
        for (int j = 0; j < DOUT; ++j) ssum += expf(lg[j] - mx);
        out[gr * DOUT + f] = expf(lg[f] - mx) / ssum;
    }
}

// ---------------- launch ----------------

extern "C" void kernel_launch(void* const* d_in, const int* in_sizes, int n_in,
                              void* d_out, int out_size, void* d_ws, size_t ws_size,
                              hipStream_t stream) {
    const float* x = (const float*)d_in[0];
    const int* edge = (const int*)d_in[1];
    const int* batch = (const int*)d_in[2];
    const float* W1 = (const float*)d_in[3];
    const float* b1 = (const float*)d_in[4];
    const float* W2 = (const float*)d_in[5];
    const float* b2 = (const float*)d_in[6];
    const float* fW1 = (const float*)d_in[7];
    const float* fb1 = (const float*)d_in[8];
    const float* fW2 = (const float*)d_in[9];
    const float* fb2 = (const float*)d_in[10];
    float* out = (float*)d_out;

    int N = in_sizes[0] / H;
    int E = in_sizes[1] / 2;
    const int* srcI = edge;
    const int* dstI = edge + E;

    char* ws = (char*)d_ws;
    size_t off = 0;
    auto alloc = [&](size_t bytes) {
        void* p = ws + off;
        off = (off + bytes + 255) & ~(size_t)255;
        return p;
    };
    int* row_ptr = (int*)alloc((size_t)(N + 1) * 4);
    int* col = (int*)alloc((size_t)E * 4);
    float* dinv = (float*)alloc((size_t)N * 4);
    int* gstart = (int*)alloc(512);
    int* bctk = (int*)alloc(192 * 4);  // bcnt[128] + tick (zeroed together)
    int* bstart = (int*)alloc((NBUCK_MAX + 1) * 4);
    int* bfill = (int*)alloc(NBUCK_MAX * 4);
    unsigned int* Wbf1 = (unsigned int*)alloc(128 * 64 * 4);
    unsigned int* Wbf2 = (unsigned int*)alloc(128 * 64 * 4);
    float* gsum = (float*)alloc((size_t)NGRAPH * H * 4);
    // A region: holds es (E*4B packed) during CSR build, then fp8 activations
    unsigned char* Af8 = (unsigned char*)alloc((size_t)N * H * 4);
    unsigned int* Bbf = (unsigned int*)alloc((size_t)N * H * 4);
    (void)ws_size;

    int* bcnt = bctk;
    int* tick = bctk + 128;
    unsigned int* es = (unsigned int*)Af8;  // consumed by sort2 before mm1 writes

    int bshift = 0;
    while (((N - 1) >> bshift) >= NBUCK_MAX) ++bshift;
    int nbuck = ((N - 1) >> bshift) + 1;

    int nst = (E + SORT_TILE - 1) / SORT_TILE;
    int nbb = (N + 255) / 256;

    hipMemsetAsync(bctk, 0, 192 * 4, stream);
    setup_kernel<<<65 + nbb + nst, 256, 0, stream>>>(batch, N, gstart, W1, W2, Wbf1, Wbf2,
                                                     gsum, dstI, E, bshift, nbuck, nbb, nst,
                                                     bcnt, tick, bstart, bfill);
    bucket_scatter_kernel<<<nst, 256, 0, stream>>>(srcI, dstI, E, bshift, bfill, es);
    bucket_sort2_kernel<<<nbuck, 1024, 0, stream>>>(es, bstart, bshift, nbuck, N, E, col,
                                                    row_ptr, dinv);

    int mmblocks = (N + 127) / 128;
    int aggblocks = (N + 7) / 8;
    mm_mfma_kernel<0><<<mmblocks, 256, 0, stream>>>(x, Wbf1, dinv, Af8, N);
    agg_fp8_kernel<<<aggblocks, 256, 0, stream>>>((const unsigned int*)Af8, row_ptr, col,
                                                  dinv, b1, Bbf, N);
    mm_mfma_kernel<1><<<mmblocks, 256, 0, stream>>>(Bbf, Wbf2, dinv, Af8, N);
    agg_fp8_kernel<<<aggblocks, 256, 0, stream>>>((const unsigned int*)Af8, row_ptr, col,
                                                  dinv, b2, Bbf, N);
    pool_partial<<<(N + 4 * PCHUNK - 1) / (4 * PCHUNK), 256, 0, stream>>>(Bbf, batch, gsum, N);
    head_kernel<<<NGRAPH, 128, 0, stream>>>(gsum, gstart, fW1, fb1, fW2, fb2, out);
}